// Round 2
// baseline (1439.897 us; speedup 1.0000x reference)
//
#include <hip/hip_runtime.h>
#include <stdint.h>

typedef __attribute__((ext_vector_type(4))) float f32x4;
typedef __attribute__((ext_vector_type(8))) __bf16 bfv8;

__device__ __forceinline__ ushort f2bf(float f) {
  union { float f; uint32_t u; } c; c.f = f;
  uint32_t u = c.u;
  uint32_t r = (u + 0x7fffu + ((u >> 16) & 1u)) >> 16;
  return (ushort)r;
}
__device__ __forceinline__ float bf2f(ushort h) {
  union { uint32_t u; float f; } c;
  c.u = ((uint32_t)h) << 16;
  return c.f;
}

// ---------------------------------------------------------------------------
// f32 -> bf16 elementwise convert (weights)
// ---------------------------------------------------------------------------
__global__ void cvt_bf16(const float* __restrict__ src, ushort* __restrict__ dst, int n4) {
  int i = blockIdx.x * blockDim.x + threadIdx.x;
  if (i < n4) {
    float4 f = ((const float4*)src)[i];
    ushort4 o;
    o.x = f2bf(f.x); o.y = f2bf(f.y); o.z = f2bf(f.z); o.w = f2bf(f.w);
    ((ushort4*)dst)[i] = o;
  }
}

// ---------------------------------------------------------------------------
// LayerNorm + time-shift + token-mix, emitting bf16 GEMM operands.
// One block per row (b,t). NOUT=3: xk,xv,xr ; NOUT=2: gk,gr (ov unused).
// ---------------------------------------------------------------------------
template <int NOUT>
__global__ __launch_bounds__(256)
void ln_mix(const float* __restrict__ x, const float* __restrict__ gam,
            const float* __restrict__ bet, const float* __restrict__ mk,
            const float* __restrict__ mv, const float* __restrict__ mr,
            ushort* __restrict__ ok, ushort* __restrict__ ov,
            ushort* __restrict__ orr, int T, int C) {
  const int row = blockIdx.x;
  const int t = row % T;
  const int tid = threadIdx.x;
  const float4* xc = (const float4*)(x + (size_t)row * C);
  float4 c4 = xc[tid];
  float4 p4 = make_float4(0.f, 0.f, 0.f, 0.f);
  if (t > 0) p4 = xc[tid - (C >> 2)];

  float s = c4.x + c4.y + c4.z + c4.w;
  float ss = c4.x * c4.x + c4.y * c4.y + c4.z * c4.z + c4.w * c4.w;
  float s2 = p4.x + p4.y + p4.z + p4.w;
  float ss2 = p4.x * p4.x + p4.y * p4.y + p4.z * p4.z + p4.w * p4.w;
#pragma unroll
  for (int off = 32; off > 0; off >>= 1) {
    s += __shfl_down(s, off);
    ss += __shfl_down(ss, off);
    s2 += __shfl_down(s2, off);
    ss2 += __shfl_down(ss2, off);
  }
  __shared__ float red[4][4];
  const int wid = tid >> 6, lane = tid & 63;
  if (lane == 0) { red[wid][0] = s; red[wid][1] = ss; red[wid][2] = s2; red[wid][3] = ss2; }
  __syncthreads();
  s = red[0][0] + red[1][0] + red[2][0] + red[3][0];
  ss = red[0][1] + red[1][1] + red[2][1] + red[3][1];
  s2 = red[0][2] + red[1][2] + red[2][2] + red[3][2];
  ss2 = red[0][3] + red[1][3] + red[2][3] + red[3][3];

  const float invC = 1.0f / (float)C;
  float m1 = s * invC, v1 = ss * invC - m1 * m1;
  float rs1 = rsqrtf(v1 + 1e-5f);
  float m2 = s2 * invC, v2 = ss2 * invC - m2 * m2;
  float rs2 = rsqrtf(v2 + 1e-5f);

  const float* c4p = (const float*)&c4;
  const float* p4p = (const float*)&p4;
  ushort4 vk, vv, vr;
#pragma unroll
  for (int j = 0; j < 4; j++) {
    int col = tid * 4 + j;
    float gg = gam[col], be = bet[col];
    float hc = (c4p[j] - m1) * rs1 * gg + be;
    float hp = (t > 0) ? ((p4p[j] - m2) * rs2 * gg + be) : 0.0f;
    float fk = mk[col];
    ((ushort*)&vk)[j] = f2bf(hc * fk + hp * (1.0f - fk));
    if constexpr (NOUT == 3) {
      float fv = mv[col];
      ((ushort*)&vv)[j] = f2bf(hc * fv + hp * (1.0f - fv));
    }
    float fr = mr[col];
    ((ushort*)&vr)[j] = f2bf(hc * fr + hp * (1.0f - fr));
  }
  size_t o = (size_t)row * (C >> 2) + tid;
  ((ushort4*)ok)[o] = vk;
  if constexpr (NOUT == 3) ((ushort4*)ov)[o] = vv;
  ((ushort4*)orr)[o] = vr;
}

// ---------------------------------------------------------------------------
// bf16 MFMA GEMM: C[M,N] = A[M,K] * W[N,K]^T  (both row-major bf16)
// 128x128 tile, BK=32, 4 waves (2x2), 4x4 16x16x32 frags per wave.
// MODE 0: out bf16 = acc
// MODE 1: out bf16 = sigmoid(acc)
// MODE 2: out bf16 = relu(acc)^2
// MODE 3: out f32 = res_f32 + acc
// MODE 4: out f32 = res_f32 + mul_bf16 * acc
// ---------------------------------------------------------------------------
template <int MODE>
__global__ __launch_bounds__(256, 2)
void gemm_bt(const ushort* __restrict__ A, const ushort* __restrict__ W,
             void* __restrict__ outp, const float* __restrict__ res,
             const ushort* __restrict__ mul, int N, int K) {
  __shared__ ushort lA[128 * 32];
  __shared__ ushort lB[128 * 32];
  const int tid = threadIdx.x;
  const int wave = tid >> 6, lane = tid & 63;
  const int rowBase = blockIdx.y * 128;
  const int colBase = blockIdx.x * 128;
  const int wr = wave >> 1, wc = wave & 1;
  const int lr = lane & 15, lk = lane >> 4;

  f32x4 acc[4][4];
#pragma unroll
  for (int m = 0; m < 4; m++)
#pragma unroll
    for (int n = 0; n < 4; n++) acc[m][n] = (f32x4){0.f, 0.f, 0.f, 0.f};

  // staging chunk ids: each thread owns chunks c0 and c0+64 of 512 (16B each)
  const int c0 = wave * 128 + lane;
  const int r0 = c0 >> 2, q0 = (c0 & 3) * 8;
  const int c1 = c0 + 64;
  const int r1 = c1 >> 2, q1 = (c1 & 3) * 8;

  for (int kt = 0; kt < K; kt += 32) {
    const ushort* gA0 = A + (size_t)(rowBase + r0) * K + kt + q0;
    const ushort* gA1 = A + (size_t)(rowBase + r1) * K + kt + q1;
    const ushort* gB0 = W + (size_t)(colBase + r0) * K + kt + q0;
    const ushort* gB1 = W + (size_t)(colBase + r1) * K + kt + q1;
    __builtin_amdgcn_global_load_lds(
        (const __attribute__((address_space(1))) void*)gA0,
        (__attribute__((address_space(3))) void*)(lA + wave * 1024), 16, 0, 0);
    __builtin_amdgcn_global_load_lds(
        (const __attribute__((address_space(1))) void*)gA1,
        (__attribute__((address_space(3))) void*)(lA + wave * 1024 + 512), 16, 0, 0);
    __builtin_amdgcn_global_load_lds(
        (const __attribute__((address_space(1))) void*)gB0,
        (__attribute__((address_space(3))) void*)(lB + wave * 1024), 16, 0, 0);
    __builtin_amdgcn_global_load_lds(
        (const __attribute__((address_space(1))) void*)gB1,
        (__attribute__((address_space(3))) void*)(lB + wave * 1024 + 512), 16, 0, 0);
    __syncthreads();

    bfv8 af[4], bfr[4];
#pragma unroll
    for (int m = 0; m < 4; m++)
      af[m] = *(const bfv8*)(lA + (wr * 64 + m * 16 + lr) * 32 + lk * 8);
#pragma unroll
    for (int n = 0; n < 4; n++)
      bfr[n] = *(const bfv8*)(lB + (wc * 64 + n * 16 + lr) * 32 + lk * 8);
#pragma unroll
    for (int m = 0; m < 4; m++)
#pragma unroll
      for (int n = 0; n < 4; n++)
        acc[m][n] = __builtin_amdgcn_mfma_f32_16x16x32_bf16(af[m], bfr[n], acc[m][n], 0, 0, 0);
    __syncthreads();
  }

#pragma unroll
  for (int m = 0; m < 4; m++) {
#pragma unroll
    for (int j = 0; j < 4; j++) {
      int row = rowBase + wr * 64 + m * 16 + lk * 4 + j;
#pragma unroll
      for (int n = 0; n < 4; n++) {
        int col = colBase + wc * 64 + n * 16 + lr;
        float v = acc[m][n][j];
        size_t idx = (size_t)row * N + col;
        if constexpr (MODE == 0) {
          ((ushort*)outp)[idx] = f2bf(v);
        } else if constexpr (MODE == 1) {
          ((ushort*)outp)[idx] = f2bf(1.0f / (1.0f + __expf(-v)));
        } else if constexpr (MODE == 2) {
          float r = fmaxf(v, 0.0f);
          ((ushort*)outp)[idx] = f2bf(r * r);
        } else if constexpr (MODE == 3) {
          ((float*)outp)[idx] = res[idx] + v;
        } else {
          ((float*)outp)[idx] = res[idx] + bf2f(mul[idx]) * v;
        }
      }
    }
  }
}

// ---------------------------------------------------------------------------
// WKV recurrence (numerically stable), one thread per (b,d) channel.
// bf16 in (k, v, sr), bf16 out: rwkv = bf16(sr * wkv)
// ---------------------------------------------------------------------------
__global__ __launch_bounds__(64)
void wkv_scan(const ushort* __restrict__ k, const ushort* __restrict__ v,
              const ushort* __restrict__ sr, const float* __restrict__ td,
              const float* __restrict__ tf, ushort* __restrict__ out,
              int T, int D) {
  int id = blockIdx.x * 64 + threadIdx.x;
  int b = id / D, d = id % D;
  float w = -__expf(td[d]);
  float u = tf[d];
  float a = 0.f, bb = 0.f, p = -1e30f;
  const size_t base = (size_t)b * T * D + d;
#pragma unroll 2
  for (int t = 0; t < T; t++) {
    size_t idx = base + (size_t)t * D;
    float kt = bf2f(k[idx]), vt = bf2f(v[idx]);
    float ww = u + kt;
    float q = fmaxf(p, ww);
    float e1 = __expf(p - q), e2 = __expf(ww - q);
    float y = (e1 * a + e2 * vt) / (e1 * bb + e2);
    out[idx] = f2bf(bf2f(sr[idx]) * y);
    float ww2 = p + w;
    float q2 = fmaxf(ww2, kt);
    float e1b = __expf(ww2 - q2), e2b = __expf(kt - q2);
    a = e1b * a + e2b * vt;
    bb = e1b * bb + e2b;
    p = q2;
  }
}

// ---------------------------------------------------------------------------
extern "C" void kernel_launch(void* const* d_in, const int* in_sizes, int n_in,
                              void* d_out, int out_size, void* d_ws, size_t ws_size,
                              hipStream_t stream) {
  (void)in_sizes; (void)n_in; (void)out_size; (void)ws_size;
  const float* x    = (const float*)d_in[0];
  const float* ln1g = (const float*)d_in[1];
  const float* ln1b = (const float*)d_in[2];
  const float* ln2g = (const float*)d_in[3];
  const float* ln2b = (const float*)d_in[4];
  const float* tmk  = (const float*)d_in[5];
  const float* tmv  = (const float*)d_in[6];
  const float* tmr  = (const float*)d_in[7];
  const float* td   = (const float*)d_in[8];
  const float* tf   = (const float*)d_in[9];
  const float* Wk   = (const float*)d_in[10];
  const float* Wv   = (const float*)d_in[11];
  const float* Wr   = (const float*)d_in[12];
  const float* Wo   = (const float*)d_in[13];
  const float* fmk  = (const float*)d_in[14];
  const float* fmr  = (const float*)d_in[15];
  const float* Fk   = (const float*)d_in[16];
  const float* Fr   = (const float*)d_in[17];
  const float* Fv   = (const float*)d_in[18];

  const int B = 8, T = 2048, C = 1024, DA = 1024, DF = 4096;
  const int M = B * T;       // 16384
  const int MQ = M / 4;      // 4096 rows per FFN quarter

  // ---- workspace layout (peak 186 MiB) ----
  char* ws = (char*)d_ws;
  const size_t MiB = 1ull << 20;
  // bf16 weights: [0, 26)
  ushort* wkb = (ushort*)(ws + 0 * MiB);
  ushort* wvb = (ushort*)(ws + 2 * MiB);
  ushort* wrb = (ushort*)(ws + 4 * MiB);
  ushort* wob = (ushort*)(ws + 6 * MiB);
  ushort* fkb = (ushort*)(ws + 8 * MiB);   // 8 MiB
  ushort* frb = (ushort*)(ws + 16 * MiB);  // 2 MiB
  ushort* fvb = (ushort*)(ws + 18 * MiB);  // 8 MiB
  // five 32 MiB bf16 regions + one more, lifetimes aliased:
  ushort* bufA = (ushort*)(ws + 26 * MiB);   // xk -> v    -> xmid(lo)
  ushort* bufB = (ushort*)(ws + 58 * MiB);   // xv -> sr   -> xmid(hi)
  ushort* bufC = (ushort*)(ws + 90 * MiB);   // xr -> rwkv -> gk
  ushort* bufD = (ushort*)(ws + 122 * MiB);  // k  -> gr   -> kf(quarter)
  ushort* bufE = (ushort*)(ws + 154 * MiB);  // sig
  float*  xmid = (float*)bufA;               // 64 MiB f32 spans A+B

  // ---- weight converts ----
  cvt_bf16<<<(DA * C / 4 + 255) / 256, 256, 0, stream>>>(Wk, wkb, DA * C / 4);
  cvt_bf16<<<(DA * C / 4 + 255) / 256, 256, 0, stream>>>(Wv, wvb, DA * C / 4);
  cvt_bf16<<<(DA * C / 4 + 255) / 256, 256, 0, stream>>>(Wr, wrb, DA * C / 4);
  cvt_bf16<<<(C * DA / 4 + 255) / 256, 256, 0, stream>>>(Wo, wob, C * DA / 4);
  cvt_bf16<<<(DF * C / 4 + 255) / 256, 256, 0, stream>>>(Fk, fkb, DF * C / 4);
  cvt_bf16<<<(C * C / 4 + 255) / 256, 256, 0, stream>>>(Fr, frb, C * C / 4);
  cvt_bf16<<<(C * DF / 4 + 255) / 256, 256, 0, stream>>>(Fv, fvb, C * DF / 4);

  // ---- TimeMix ----
  ushort* xk = bufA; ushort* xv = bufB; ushort* xr = bufC;
  ln_mix<3><<<M, 256, 0, stream>>>(x, ln1g, ln1b, tmk, tmv, tmr, xk, xv, xr, T, C);

  ushort* kb = bufD; ushort* vb = bufA; ushort* srb = bufB; ushort* rwkv = bufC;
  dim3 gA(DA / 128, M / 128);
  gemm_bt<0><<<gA, 256, 0, stream>>>(xk, wkb, kb, nullptr, nullptr, DA, C);   // k (A dead after)
  gemm_bt<0><<<gA, 256, 0, stream>>>(xv, wvb, vb, nullptr, nullptr, DA, C);   // v -> A
  gemm_bt<1><<<gA, 256, 0, stream>>>(xr, wrb, srb, nullptr, nullptr, DA, C);  // sr -> B

  wkv_scan<<<(B * DA) / 64, 64, 0, stream>>>(kb, vb, srb, td, tf, rwkv, T, DA);  // -> C

  // xmid = x + rwkv @ Wo^T   (f32, spans A+B; v/sr dead)
  gemm_bt<3><<<dim3(C / 128, M / 128), 256, 0, stream>>>(rwkv, wob, xmid, x, nullptr, C, DA);

  // ---- ChannelMix ----
  ushort* gk = bufC; ushort* gr = bufD; ushort* sig = bufE;
  ln_mix<2><<<M, 256, 0, stream>>>(xmid, ln2g, ln2b, fmk, nullptr, fmr, gk, nullptr, gr, T, C);

  // sig = sigmoid(gr @ Fr^T)  -> E  (then gr dead)
  gemm_bt<1><<<dim3(C / 128, M / 128), 256, 0, stream>>>(gr, frb, sig, nullptr, nullptr, C, C);

  // FFN in 4 row-quarters to keep kf at 32 MiB (bufD, gr dead)
  ushort* kf = bufD;
  for (int q = 0; q < 4; q++) {
    const ushort* gkq = gk + (size_t)q * MQ * C;
    gemm_bt<2><<<dim3(DF / 128, MQ / 128), 256, 0, stream>>>(gkq, fkb, kf, nullptr, nullptr, DF, C);
    gemm_bt<4><<<dim3(C / 128, MQ / 128), 256, 0, stream>>>(
        kf, fvb, (float*)d_out + (size_t)q * MQ * C,
        xmid + (size_t)q * MQ * C, sig + (size_t)q * MQ * C, C, DF);
  }
}

// Round 3
// 1064.348 us; speedup vs baseline: 1.3528x; 1.3528x over previous
//
#include <hip/hip_runtime.h>
#include <stdint.h>

typedef __attribute__((ext_vector_type(4))) float f32x4;
typedef __attribute__((ext_vector_type(8))) __bf16 bfv8;

__device__ __forceinline__ ushort f2bf(float f) {
  union { float f; uint32_t u; } c; c.f = f;
  uint32_t u = c.u;
  uint32_t r = (u + 0x7fffu + ((u >> 16) & 1u)) >> 16;
  return (ushort)r;
}
__device__ __forceinline__ float bf2f(ushort h) {
  union { uint32_t u; float f; } c;
  c.u = ((uint32_t)h) << 16;
  return c.f;
}

// ---------------------------------------------------------------------------
// f32 -> bf16 elementwise convert (weights)
// ---------------------------------------------------------------------------
__global__ void cvt_bf16(const float* __restrict__ src, ushort* __restrict__ dst, int n4) {
  int i = blockIdx.x * blockDim.x + threadIdx.x;
  if (i < n4) {
    float4 f = ((const float4*)src)[i];
    ushort4 o;
    o.x = f2bf(f.x); o.y = f2bf(f.y); o.z = f2bf(f.z); o.w = f2bf(f.w);
    ((ushort4*)dst)[i] = o;
  }
}

// ---------------------------------------------------------------------------
// LayerNorm + time-shift + token-mix, emitting bf16 GEMM operands.
// ---------------------------------------------------------------------------
template <int NOUT>
__global__ __launch_bounds__(256)
void ln_mix(const float* __restrict__ x, const float* __restrict__ gam,
            const float* __restrict__ bet, const float* __restrict__ mk,
            const float* __restrict__ mv, const float* __restrict__ mr,
            ushort* __restrict__ ok, ushort* __restrict__ ov,
            ushort* __restrict__ orr, int T, int C) {
  const int row = blockIdx.x;
  const int t = row % T;
  const int tid = threadIdx.x;
  const float4* xc = (const float4*)(x + (size_t)row * C);
  float4 c4 = xc[tid];
  float4 p4 = make_float4(0.f, 0.f, 0.f, 0.f);
  if (t > 0) p4 = xc[tid - (C >> 2)];

  float s = c4.x + c4.y + c4.z + c4.w;
  float ss = c4.x * c4.x + c4.y * c4.y + c4.z * c4.z + c4.w * c4.w;
  float s2 = p4.x + p4.y + p4.z + p4.w;
  float ss2 = p4.x * p4.x + p4.y * p4.y + p4.z * p4.z + p4.w * p4.w;
#pragma unroll
  for (int off = 32; off > 0; off >>= 1) {
    s += __shfl_down(s, off);
    ss += __shfl_down(ss, off);
    s2 += __shfl_down(s2, off);
    ss2 += __shfl_down(ss2, off);
  }
  __shared__ float red[4][4];
  const int wid = tid >> 6, lane = tid & 63;
  if (lane == 0) { red[wid][0] = s; red[wid][1] = ss; red[wid][2] = s2; red[wid][3] = ss2; }
  __syncthreads();
  s = red[0][0] + red[1][0] + red[2][0] + red[3][0];
  ss = red[0][1] + red[1][1] + red[2][1] + red[3][1];
  s2 = red[0][2] + red[1][2] + red[2][2] + red[3][2];
  ss2 = red[0][3] + red[1][3] + red[2][3] + red[3][3];

  const float invC = 1.0f / (float)C;
  float m1 = s * invC, v1 = ss * invC - m1 * m1;
  float rs1 = rsqrtf(v1 + 1e-5f);
  float m2 = s2 * invC, v2 = ss2 * invC - m2 * m2;
  float rs2 = rsqrtf(v2 + 1e-5f);

  const float* c4p = (const float*)&c4;
  const float* p4p = (const float*)&p4;
  ushort4 vk, vv, vr;
#pragma unroll
  for (int j = 0; j < 4; j++) {
    int col = tid * 4 + j;
    float gg = gam[col], be = bet[col];
    float hc = (c4p[j] - m1) * rs1 * gg + be;
    float hp = (t > 0) ? ((p4p[j] - m2) * rs2 * gg + be) : 0.0f;
    float fk = mk[col];
    ((ushort*)&vk)[j] = f2bf(hc * fk + hp * (1.0f - fk));
    if constexpr (NOUT == 3) {
      float fv = mv[col];
      ((ushort*)&vv)[j] = f2bf(hc * fv + hp * (1.0f - fv));
    }
    float fr = mr[col];
    ((ushort*)&vr)[j] = f2bf(hc * fr + hp * (1.0f - fr));
  }
  size_t o = (size_t)row * (C >> 2) + tid;
  ((ushort4*)ok)[o] = vk;
  if constexpr (NOUT == 3) ((ushort4*)ov)[o] = vv;
  ((ushort4*)orr)[o] = vr;
}

// ---------------------------------------------------------------------------
// bf16 MFMA GEMM: C[M,N] = A[M,K] * W[N,K]^T  (both row-major bf16)
// ---------------------------------------------------------------------------
template <int MODE>
__global__ __launch_bounds__(256, 2)
void gemm_bt(const ushort* __restrict__ A, const ushort* __restrict__ W,
             void* __restrict__ outp, const float* __restrict__ res,
             const ushort* __restrict__ mul, int N, int K) {
  __shared__ ushort lA[128 * 32];
  __shared__ ushort lB[128 * 32];
  const int tid = threadIdx.x;
  const int wave = tid >> 6, lane = tid & 63;
  const int rowBase = blockIdx.y * 128;
  const int colBase = blockIdx.x * 128;
  const int wr = wave >> 1, wc = wave & 1;
  const int lr = lane & 15, lk = lane >> 4;

  f32x4 acc[4][4];
#pragma unroll
  for (int m = 0; m < 4; m++)
#pragma unroll
    for (int n = 0; n < 4; n++) acc[m][n] = (f32x4){0.f, 0.f, 0.f, 0.f};

  const int c0 = wave * 128 + lane;
  const int r0 = c0 >> 2, q0 = (c0 & 3) * 8;
  const int c1 = c0 + 64;
  const int r1 = c1 >> 2, q1 = (c1 & 3) * 8;

  for (int kt = 0; kt < K; kt += 32) {
    const ushort* gA0 = A + (size_t)(rowBase + r0) * K + kt + q0;
    const ushort* gA1 = A + (size_t)(rowBase + r1) * K + kt + q1;
    const ushort* gB0 = W + (size_t)(colBase + r0) * K + kt + q0;
    const ushort* gB1 = W + (size_t)(colBase + r1) * K + kt + q1;
    __builtin_amdgcn_global_load_lds(
        (const __attribute__((address_space(1))) void*)gA0,
        (__attribute__((address_space(3))) void*)(lA + wave * 1024), 16, 0, 0);
    __builtin_amdgcn_global_load_lds(
        (const __attribute__((address_space(1))) void*)gA1,
        (__attribute__((address_space(3))) void*)(lA + wave * 1024 + 512), 16, 0, 0);
    __builtin_amdgcn_global_load_lds(
        (const __attribute__((address_space(1))) void*)gB0,
        (__attribute__((address_space(3))) void*)(lB + wave * 1024), 16, 0, 0);
    __builtin_amdgcn_global_load_lds(
        (const __attribute__((address_space(1))) void*)gB1,
        (__attribute__((address_space(3))) void*)(lB + wave * 1024 + 512), 16, 0, 0);
    __syncthreads();

    bfv8 af[4], bfr[4];
#pragma unroll
    for (int m = 0; m < 4; m++)
      af[m] = *(const bfv8*)(lA + (wr * 64 + m * 16 + lr) * 32 + lk * 8);
#pragma unroll
    for (int n = 0; n < 4; n++)
      bfr[n] = *(const bfv8*)(lB + (wc * 64 + n * 16 + lr) * 32 + lk * 8);
#pragma unroll
    for (int m = 0; m < 4; m++)
#pragma unroll
      for (int n = 0; n < 4; n++)
        acc[m][n] = __builtin_amdgcn_mfma_f32_16x16x32_bf16(af[m], bfr[n], acc[m][n], 0, 0, 0);
    __syncthreads();
  }

#pragma unroll
  for (int m = 0; m < 4; m++) {
#pragma unroll
    for (int j = 0; j < 4; j++) {
      int row = rowBase + wr * 64 + m * 16 + lk * 4 + j;
#pragma unroll
      for (int n = 0; n < 4; n++) {
        int col = colBase + wc * 64 + n * 16 + lr;
        float v = acc[m][n][j];
        size_t idx = (size_t)row * N + col;
        if constexpr (MODE == 0) {
          ((ushort*)outp)[idx] = f2bf(v);
        } else if constexpr (MODE == 1) {
          ((ushort*)outp)[idx] = f2bf(1.0f / (1.0f + __expf(-v)));
        } else if constexpr (MODE == 2) {
          float r = fmaxf(v, 0.0f);
          ((ushort*)outp)[idx] = f2bf(r * r);
        } else if constexpr (MODE == 3) {
          ((float*)outp)[idx] = res[idx] + v;
        } else {
          ((float*)outp)[idx] = res[idx] + bf2f(mul[idx]) * v;
        }
      }
    }
  }
}

// ---------------------------------------------------------------------------
// WKV chunk-parallel scan. T split into NCH chunks of L.
// State (a,b,p): a,b scaled by exp(p);  p_t = max(p_{t-1}+w, k_t).
// ---------------------------------------------------------------------------
#define WKV_NCH 32
#define WKV_L 64

// Phase 1: per-(b,chunk,d) local state from zero init.
__global__ __launch_bounds__(256)
void wkv_phase1(const ushort* __restrict__ k, const ushort* __restrict__ v,
                const float* __restrict__ td,
                float* __restrict__ sA, float* __restrict__ sB, float* __restrict__ sP,
                int T, int D) {
  int id = blockIdx.x * 256 + threadIdx.x;  // ((b*NCH + c)*D + d)
  int d = id % D;
  int bc = id / D;
  int c = bc % WKV_NCH;
  int b = bc / WKV_NCH;
  float w = -__expf(td[d]);
  float a = 0.f, bb = 0.f, p = -1e30f;
  const size_t base = (size_t)b * T * D + (size_t)c * WKV_L * D + d;
#pragma unroll 4
  for (int t = 0; t < WKV_L; t++) {
    size_t idx = base + (size_t)t * D;
    float kt = bf2f(k[idx]), vt = bf2f(v[idx]);
    float ww2 = p + w;
    float q2 = fmaxf(ww2, kt);
    float e1b = __expf(ww2 - q2), e2b = __expf(kt - q2);
    a = e1b * a + e2b * vt;
    bb = e1b * bb + e2b;
    p = q2;
  }
  sA[id] = a; sB[id] = bb; sP[id] = p;
}

// Phase 2: per-(b,d) serial prefix combine; rewrites sA/sB/sP with the
// INCOMING state for each chunk.
__global__ __launch_bounds__(256)
void wkv_combine(const float* __restrict__ td,
                 float* __restrict__ sA, float* __restrict__ sB, float* __restrict__ sP,
                 int D) {
  int id = blockIdx.x * 256 + threadIdx.x;  // b*D + d
  int d = id % D;
  int b = id / D;
  float w = -__expf(td[d]);
  float Lw = (float)WKV_L * w;
  float a = 0.f, bb = 0.f, p = -1e30f;
  for (int c = 0; c < WKV_NCH; c++) {
    size_t idx = ((size_t)b * WKV_NCH + c) * D + d;
    float la = sA[idx], lb = sB[idx], lp = sP[idx];
    sA[idx] = a; sB[idx] = bb; sP[idx] = p;
    // prefix = decay(prefix, L) merge local
    float pd = p + Lw;
    float q = fmaxf(pd, lp);
    float e1 = __expf(pd - q), e2 = __expf(lp - q);
    a = e1 * a + e2 * la;
    bb = e1 * bb + e2 * lb;
    p = q;
  }
}

// Phase 3: replay chunk with true incoming state, emit bf16(sr*y).
__global__ __launch_bounds__(256)
void wkv_phase3(const ushort* __restrict__ k, const ushort* __restrict__ v,
                const ushort* __restrict__ sr, const float* __restrict__ td,
                const float* __restrict__ tf,
                const float* __restrict__ sA, const float* __restrict__ sB,
                const float* __restrict__ sP, ushort* __restrict__ out,
                int T, int D) {
  int id = blockIdx.x * 256 + threadIdx.x;  // ((b*NCH + c)*D + d)
  int d = id % D;
  int bc = id / D;
  int c = bc % WKV_NCH;
  int b = bc / WKV_NCH;
  float w = -__expf(td[d]);
  float u = tf[d];
  float a = sA[id], bb = sB[id], p = sP[id];
  const size_t base = (size_t)b * T * D + (size_t)c * WKV_L * D + d;
#pragma unroll 2
  for (int t = 0; t < WKV_L; t++) {
    size_t idx = base + (size_t)t * D;
    float kt = bf2f(k[idx]), vt = bf2f(v[idx]);
    float ww = u + kt;
    float q = fmaxf(p, ww);
    float e1 = __expf(p - q), e2 = __expf(ww - q);
    float y = (e1 * a + e2 * vt) / (e1 * bb + e2);
    out[idx] = f2bf(bf2f(sr[idx]) * y);
    float ww2 = p + w;
    float q2 = fmaxf(ww2, kt);
    float e1b = __expf(ww2 - q2), e2b = __expf(kt - q2);
    a = e1b * a + e2b * vt;
    bb = e1b * bb + e2b;
    p = q2;
  }
}

// ---------------------------------------------------------------------------
extern "C" void kernel_launch(void* const* d_in, const int* in_sizes, int n_in,
                              void* d_out, int out_size, void* d_ws, size_t ws_size,
                              hipStream_t stream) {
  (void)in_sizes; (void)n_in; (void)out_size; (void)ws_size;
  const float* x    = (const float*)d_in[0];
  const float* ln1g = (const float*)d_in[1];
  const float* ln1b = (const float*)d_in[2];
  const float* ln2g = (const float*)d_in[3];
  const float* ln2b = (const float*)d_in[4];
  const float* tmk  = (const float*)d_in[5];
  const float* tmv  = (const float*)d_in[6];
  const float* tmr  = (const float*)d_in[7];
  const float* td   = (const float*)d_in[8];
  const float* tf   = (const float*)d_in[9];
  const float* Wk   = (const float*)d_in[10];
  const float* Wv   = (const float*)d_in[11];
  const float* Wr   = (const float*)d_in[12];
  const float* Wo   = (const float*)d_in[13];
  const float* fmk  = (const float*)d_in[14];
  const float* fmr  = (const float*)d_in[15];
  const float* Fk   = (const float*)d_in[16];
  const float* Fr   = (const float*)d_in[17];
  const float* Fv   = (const float*)d_in[18];

  const int B = 8, T = 2048, C = 1024, DA = 1024, DF = 4096;
  const int M = B * T;       // 16384
  const int MQ = M / 4;      // 4096 rows per FFN quarter

  // ---- workspace layout (peak 189 MiB) ----
  char* ws = (char*)d_ws;
  const size_t MiB = 1ull << 20;
  ushort* wkb = (ushort*)(ws + 0 * MiB);
  ushort* wvb = (ushort*)(ws + 2 * MiB);
  ushort* wrb = (ushort*)(ws + 4 * MiB);
  ushort* wob = (ushort*)(ws + 6 * MiB);
  ushort* fkb = (ushort*)(ws + 8 * MiB);   // 8 MiB
  ushort* frb = (ushort*)(ws + 16 * MiB);  // 2 MiB
  ushort* fvb = (ushort*)(ws + 18 * MiB);  // 8 MiB
  ushort* bufA = (ushort*)(ws + 26 * MiB);   // xk -> v    -> xmid(lo)
  ushort* bufB = (ushort*)(ws + 58 * MiB);   // xv -> sr   -> xmid(hi)
  ushort* bufC = (ushort*)(ws + 90 * MiB);   // xr -> rwkv -> gk
  ushort* bufD = (ushort*)(ws + 122 * MiB);  // k  -> gr   -> kf(quarter)
  ushort* bufE = (ushort*)(ws + 154 * MiB);  // sig
  float*  xmid = (float*)bufA;               // 64 MiB f32 spans A+B
  float*  sAa  = (float*)(ws + 186 * MiB);   // 1 MiB each chunk-state array
  float*  sBb  = (float*)(ws + 187 * MiB);
  float*  sPp  = (float*)(ws + 188 * MiB);

  // ---- weight converts ----
  cvt_bf16<<<(DA * C / 4 + 255) / 256, 256, 0, stream>>>(Wk, wkb, DA * C / 4);
  cvt_bf16<<<(DA * C / 4 + 255) / 256, 256, 0, stream>>>(Wv, wvb, DA * C / 4);
  cvt_bf16<<<(DA * C / 4 + 255) / 256, 256, 0, stream>>>(Wr, wrb, DA * C / 4);
  cvt_bf16<<<(C * DA / 4 + 255) / 256, 256, 0, stream>>>(Wo, wob, C * DA / 4);
  cvt_bf16<<<(DF * C / 4 + 255) / 256, 256, 0, stream>>>(Fk, fkb, DF * C / 4);
  cvt_bf16<<<(C * C / 4 + 255) / 256, 256, 0, stream>>>(Fr, frb, C * C / 4);
  cvt_bf16<<<(C * DF / 4 + 255) / 256, 256, 0, stream>>>(Fv, fvb, C * DF / 4);

  // ---- TimeMix ----
  ushort* xk = bufA; ushort* xv = bufB; ushort* xr = bufC;
  ln_mix<3><<<M, 256, 0, stream>>>(x, ln1g, ln1b, tmk, tmv, tmr, xk, xv, xr, T, C);

  ushort* kb = bufD; ushort* vb = bufA; ushort* srb = bufB; ushort* rwkv = bufC;
  dim3 gA(DA / 128, M / 128);
  gemm_bt<0><<<gA, 256, 0, stream>>>(xk, wkb, kb, nullptr, nullptr, DA, C);   // k (A dead after)
  gemm_bt<0><<<gA, 256, 0, stream>>>(xv, wvb, vb, nullptr, nullptr, DA, C);   // v -> A
  gemm_bt<1><<<gA, 256, 0, stream>>>(xr, wrb, srb, nullptr, nullptr, DA, C);  // sr -> B

  // chunk-parallel WKV
  wkv_phase1<<<(B * WKV_NCH * DA) / 256, 256, 0, stream>>>(kb, vb, td, sAa, sBb, sPp, T, DA);
  wkv_combine<<<(B * DA) / 256, 256, 0, stream>>>(td, sAa, sBb, sPp, DA);
  wkv_phase3<<<(B * WKV_NCH * DA) / 256, 256, 0, stream>>>(kb, vb, srb, td, tf, sAa, sBb, sPp, rwkv, T, DA);

  // xmid = x + rwkv @ Wo^T   (f32, spans A+B; v/sr dead)
  gemm_bt<3><<<dim3(C / 128, M / 128), 256, 0, stream>>>(rwkv, wob, xmid, x, nullptr, C, DA);

  // ---- ChannelMix ----
  ushort* gk = bufC; ushort* gr = bufD; ushort* sig = bufE;
  ln_mix<2><<<M, 256, 0, stream>>>(xmid, ln2g, ln2b, fmk, nullptr, fmr, gk, nullptr, gr, T, C);

  // sig = sigmoid(gr @ Fr^T)  -> E  (then gr dead)
  gemm_bt<1><<<dim3(C / 128, M / 128), 256, 0, stream>>>(gr, frb, sig, nullptr, nullptr, C, C);

  // FFN in 4 row-quarters to keep kf at 32 MiB (bufD, gr dead)
  ushort* kf = bufD;
  for (int q = 0; q < 4; q++) {
    const ushort* gkq = gk + (size_t)q * MQ * C;
    gemm_bt<2><<<dim3(DF / 128, MQ / 128), 256, 0, stream>>>(gkq, fkb, kf, nullptr, nullptr, DF, C);
    gemm_bt<4><<<dim3(C / 128, MQ / 128), 256, 0, stream>>>(
        kf, fvb, (float*)d_out + (size_t)q * MQ * C,
        xmid + (size_t)q * MQ * C, sig + (size_t)q * MQ * C, C, DF);
  }
}

// Round 4
// 1008.388 us; speedup vs baseline: 1.4279x; 1.0555x over previous
//
#include <hip/hip_runtime.h>
#include <stdint.h>

typedef __attribute__((ext_vector_type(4))) float f32x4;
typedef __attribute__((ext_vector_type(8))) __bf16 bfv8;

__device__ __forceinline__ ushort f2bf(float f) {
  union { float f; uint32_t u; } c; c.f = f;
  uint32_t u = c.u;
  uint32_t r = (u + 0x7fffu + ((u >> 16) & 1u)) >> 16;
  return (ushort)r;
}
__device__ __forceinline__ float bf2f(ushort h) {
  union { uint32_t u; float f; } c;
  c.u = ((uint32_t)h) << 16;
  return c.f;
}

// ---------------------------------------------------------------------------
// f32 -> bf16 elementwise convert (weights)
// ---------------------------------------------------------------------------
__global__ void cvt_bf16(const float* __restrict__ src, ushort* __restrict__ dst, int n4) {
  int i = blockIdx.x * blockDim.x + threadIdx.x;
  if (i < n4) {
    float4 f = ((const float4*)src)[i];
    ushort4 o;
    o.x = f2bf(f.x); o.y = f2bf(f.y); o.z = f2bf(f.z); o.w = f2bf(f.w);
    ((ushort4*)dst)[i] = o;
  }
}

// ---------------------------------------------------------------------------
// LayerNorm + time-shift + token-mix, emitting bf16 GEMM operands.
// ---------------------------------------------------------------------------
template <int NOUT>
__global__ __launch_bounds__(256)
void ln_mix(const float* __restrict__ x, const float* __restrict__ gam,
            const float* __restrict__ bet, const float* __restrict__ mk,
            const float* __restrict__ mv, const float* __restrict__ mr,
            ushort* __restrict__ ok, ushort* __restrict__ ov,
            ushort* __restrict__ orr, int T, int C) {
  const int row = blockIdx.x;
  const int t = row % T;
  const int tid = threadIdx.x;
  const float4* xc = (const float4*)(x + (size_t)row * C);
  float4 c4 = xc[tid];
  float4 p4 = make_float4(0.f, 0.f, 0.f, 0.f);
  if (t > 0) p4 = xc[tid - (C >> 2)];

  float s = c4.x + c4.y + c4.z + c4.w;
  float ss = c4.x * c4.x + c4.y * c4.y + c4.z * c4.z + c4.w * c4.w;
  float s2 = p4.x + p4.y + p4.z + p4.w;
  float ss2 = p4.x * p4.x + p4.y * p4.y + p4.z * p4.z + p4.w * p4.w;
#pragma unroll
  for (int off = 32; off > 0; off >>= 1) {
    s += __shfl_down(s, off);
    ss += __shfl_down(ss, off);
    s2 += __shfl_down(s2, off);
    ss2 += __shfl_down(ss2, off);
  }
  __shared__ float red[4][4];
  const int wid = tid >> 6, lane = tid & 63;
  if (lane == 0) { red[wid][0] = s; red[wid][1] = ss; red[wid][2] = s2; red[wid][3] = ss2; }
  __syncthreads();
  s = red[0][0] + red[1][0] + red[2][0] + red[3][0];
  ss = red[0][1] + red[1][1] + red[2][1] + red[3][1];
  s2 = red[0][2] + red[1][2] + red[2][2] + red[3][2];
  ss2 = red[0][3] + red[1][3] + red[2][3] + red[3][3];

  const float invC = 1.0f / (float)C;
  float m1 = s * invC, v1 = ss * invC - m1 * m1;
  float rs1 = rsqrtf(v1 + 1e-5f);
  float m2 = s2 * invC, v2 = ss2 * invC - m2 * m2;
  float rs2 = rsqrtf(v2 + 1e-5f);

  const float* c4p = (const float*)&c4;
  const float* p4p = (const float*)&p4;
  ushort4 vk, vv, vr;
#pragma unroll
  for (int j = 0; j < 4; j++) {
    int col = tid * 4 + j;
    float gg = gam[col], be = bet[col];
    float hc = (c4p[j] - m1) * rs1 * gg + be;
    float hp = (t > 0) ? ((p4p[j] - m2) * rs2 * gg + be) : 0.0f;
    float fk = mk[col];
    ((ushort*)&vk)[j] = f2bf(hc * fk + hp * (1.0f - fk));
    if constexpr (NOUT == 3) {
      float fv = mv[col];
      ((ushort*)&vv)[j] = f2bf(hc * fv + hp * (1.0f - fv));
    }
    float fr = mr[col];
    ((ushort*)&vr)[j] = f2bf(hc * fr + hp * (1.0f - fr));
  }
  size_t o = (size_t)row * (C >> 2) + tid;
  ((ushort4*)ok)[o] = vk;
  if constexpr (NOUT == 3) ((ushort4*)ov)[o] = vv;
  ((ushort4*)orr)[o] = vr;
}

// ---------------------------------------------------------------------------
// bf16 MFMA GEMM: C[M,N] = A[M,K] * W[N,K]^T  (both row-major bf16)
// 128x128 tile, BK=32, 4 waves (2x2), double-buffered LDS, 2-phase pipeline
// (stage next K-tile before computing current; one barrier per K-step),
// XCD-aware bijective block swizzle (grids must have nwg % 8 == 0).
// ---------------------------------------------------------------------------
template <int MODE>
__global__ __launch_bounds__(256, 2)
void gemm_bt(const ushort* __restrict__ A, const ushort* __restrict__ W,
             void* __restrict__ outp, const float* __restrict__ res,
             const ushort* __restrict__ mul, int N, int K) {
  __shared__ ushort lA[2][4096];
  __shared__ ushort lB[2][4096];
  const int tid = threadIdx.x;
  const int wave = tid >> 6, lane = tid & 63;

  // XCD-aware swizzle: consecutive logical tiles -> same XCD (L2 reuse of A)
  const int nwg = gridDim.x * gridDim.y;
  const int bid = blockIdx.y * gridDim.x + blockIdx.x;
  const int swz = (bid & 7) * (nwg >> 3) + (bid >> 3);
  const int rowBase = (swz / gridDim.x) * 128;
  const int colBase = (swz % gridDim.x) * 128;

  const int wr = wave >> 1, wc = wave & 1;
  const int lr = lane & 15, lk = lane >> 4;

  f32x4 acc[4][4];
#pragma unroll
  for (int m = 0; m < 4; m++)
#pragma unroll
    for (int n = 0; n < 4; n++) acc[m][n] = (f32x4){0.f, 0.f, 0.f, 0.f};

  // staging chunk ids: each thread owns chunks c0 and c0+64 of 512 (16B each)
  const int c0 = wave * 128 + lane;
  const int r0 = c0 >> 2, q0 = (c0 & 3) * 8;
  const int c1 = c0 + 64;
  const int r1 = c1 >> 2, q1 = (c1 & 3) * 8;

  auto stage = [&](int buf, int kt) {
    const ushort* gA0 = A + (size_t)(rowBase + r0) * K + kt + q0;
    const ushort* gA1 = A + (size_t)(rowBase + r1) * K + kt + q1;
    const ushort* gB0 = W + (size_t)(colBase + r0) * K + kt + q0;
    const ushort* gB1 = W + (size_t)(colBase + r1) * K + kt + q1;
    ushort* dA = &lA[buf][wave * 1024];
    ushort* dB = &lB[buf][wave * 1024];
    __builtin_amdgcn_global_load_lds(
        (const __attribute__((address_space(1))) void*)gA0,
        (__attribute__((address_space(3))) void*)dA, 16, 0, 0);
    __builtin_amdgcn_global_load_lds(
        (const __attribute__((address_space(1))) void*)gA1,
        (__attribute__((address_space(3))) void*)(dA + 512), 16, 0, 0);
    __builtin_amdgcn_global_load_lds(
        (const __attribute__((address_space(1))) void*)gB0,
        (__attribute__((address_space(3))) void*)dB, 16, 0, 0);
    __builtin_amdgcn_global_load_lds(
        (const __attribute__((address_space(1))) void*)gB1,
        (__attribute__((address_space(3))) void*)(dB + 512), 16, 0, 0);
  };

  auto compute = [&](int buf) {
    bfv8 af[4], bfr[4];
#pragma unroll
    for (int m = 0; m < 4; m++)
      af[m] = *(const bfv8*)(&lA[buf][(wr * 64 + m * 16 + lr) * 32 + lk * 8]);
#pragma unroll
    for (int n = 0; n < 4; n++)
      bfr[n] = *(const bfv8*)(&lB[buf][(wc * 64 + n * 16 + lr) * 32 + lk * 8]);
#pragma unroll
    for (int m = 0; m < 4; m++)
#pragma unroll
      for (int n = 0; n < 4; n++)
        acc[m][n] = __builtin_amdgcn_mfma_f32_16x16x32_bf16(af[m], bfr[n], acc[m][n], 0, 0, 0);
  };

  // 2-phase pipeline: prologue stage tile0; per step stage(next) || compute(cur)
  stage(0, 0);
  __syncthreads();  // implicit vmcnt(0) drain
  int cur = 0;
  for (int kt = 0; kt + 32 < K; kt += 32) {
    stage(cur ^ 1, kt + 32);
    compute(cur);
    __syncthreads();  // drains next-tile staging; fences buffer reuse
    cur ^= 1;
  }
  compute(cur);

#pragma unroll
  for (int m = 0; m < 4; m++) {
#pragma unroll
    for (int j = 0; j < 4; j++) {
      int row = rowBase + wr * 64 + m * 16 + lk * 4 + j;
#pragma unroll
      for (int n = 0; n < 4; n++) {
        int col = colBase + wc * 64 + n * 16 + lr;
        float v = acc[m][n][j];
        size_t idx = (size_t)row * N + col;
        if constexpr (MODE == 0) {
          ((ushort*)outp)[idx] = f2bf(v);
        } else if constexpr (MODE == 1) {
          ((ushort*)outp)[idx] = f2bf(1.0f / (1.0f + __expf(-v)));
        } else if constexpr (MODE == 2) {
          float r = fmaxf(v, 0.0f);
          ((ushort*)outp)[idx] = f2bf(r * r);
        } else if constexpr (MODE == 3) {
          ((float*)outp)[idx] = res[idx] + v;
        } else {
          ((float*)outp)[idx] = res[idx] + bf2f(mul[idx]) * v;
        }
      }
    }
  }
}

// ---------------------------------------------------------------------------
// WKV chunk-parallel scan. T split into NCH chunks of L.
// ---------------------------------------------------------------------------
#define WKV_NCH 32
#define WKV_L 64

__global__ __launch_bounds__(256)
void wkv_phase1(const ushort* __restrict__ k, const ushort* __restrict__ v,
                const float* __restrict__ td,
                float* __restrict__ sA, float* __restrict__ sB, float* __restrict__ sP,
                int T, int D) {
  int id = blockIdx.x * 256 + threadIdx.x;  // ((b*NCH + c)*D + d)
  int d = id % D;
  int bc = id / D;
  int c = bc % WKV_NCH;
  int b = bc / WKV_NCH;
  float w = -__expf(td[d]);
  float a = 0.f, bb = 0.f, p = -1e30f;
  const size_t base = (size_t)b * T * D + (size_t)c * WKV_L * D + d;
#pragma unroll 4
  for (int t = 0; t < WKV_L; t++) {
    size_t idx = base + (size_t)t * D;
    float kt = bf2f(k[idx]), vt = bf2f(v[idx]);
    float ww2 = p + w;
    float q2 = fmaxf(ww2, kt);
    float e1b = __expf(ww2 - q2), e2b = __expf(kt - q2);
    a = e1b * a + e2b * vt;
    bb = e1b * bb + e2b;
    p = q2;
  }
  sA[id] = a; sB[id] = bb; sP[id] = p;
}

__global__ __launch_bounds__(256)
void wkv_combine(const float* __restrict__ td,
                 float* __restrict__ sA, float* __restrict__ sB, float* __restrict__ sP,
                 int D) {
  int id = blockIdx.x * 256 + threadIdx.x;  // b*D + d
  int d = id % D;
  int b = id / D;
  float w = -__expf(td[d]);
  float Lw = (float)WKV_L * w;
  float a = 0.f, bb = 0.f, p = -1e30f;
  for (int c = 0; c < WKV_NCH; c++) {
    size_t idx = ((size_t)b * WKV_NCH + c) * D + d;
    float la = sA[idx], lb = sB[idx], lp = sP[idx];
    sA[idx] = a; sB[idx] = bb; sP[idx] = p;
    float pd = p + Lw;
    float q = fmaxf(pd, lp);
    float e1 = __expf(pd - q), e2 = __expf(lp - q);
    a = e1 * a + e2 * la;
    bb = e1 * bb + e2 * lb;
    p = q;
  }
}

__global__ __launch_bounds__(256)
void wkv_phase3(const ushort* __restrict__ k, const ushort* __restrict__ v,
                const ushort* __restrict__ sr, const float* __restrict__ td,
                const float* __restrict__ tf,
                const float* __restrict__ sA, const float* __restrict__ sB,
                const float* __restrict__ sP, ushort* __restrict__ out,
                int T, int D) {
  int id = blockIdx.x * 256 + threadIdx.x;  // ((b*NCH + c)*D + d)
  int d = id % D;
  int bc = id / D;
  int c = bc % WKV_NCH;
  int b = bc / WKV_NCH;
  float w = -__expf(td[d]);
  float u = tf[d];
  float a = sA[id], bb = sB[id], p = sP[id];
  const size_t base = (size_t)b * T * D + (size_t)c * WKV_L * D + d;
#pragma unroll 2
  for (int t = 0; t < WKV_L; t++) {
    size_t idx = base + (size_t)t * D;
    float kt = bf2f(k[idx]), vt = bf2f(v[idx]);
    float ww = u + kt;
    float q = fmaxf(p, ww);
    float e1 = __expf(p - q), e2 = __expf(ww - q);
    float y = (e1 * a + e2 * vt) / (e1 * bb + e2);
    out[idx] = f2bf(bf2f(sr[idx]) * y);
    float ww2 = p + w;
    float q2 = fmaxf(ww2, kt);
    float e1b = __expf(ww2 - q2), e2b = __expf(kt - q2);
    a = e1b * a + e2b * vt;
    bb = e1b * bb + e2b;
    p = q2;
  }
}

// ---------------------------------------------------------------------------
extern "C" void kernel_launch(void* const* d_in, const int* in_sizes, int n_in,
                              void* d_out, int out_size, void* d_ws, size_t ws_size,
                              hipStream_t stream) {
  (void)in_sizes; (void)n_in; (void)out_size; (void)ws_size;
  const float* x    = (const float*)d_in[0];
  const float* ln1g = (const float*)d_in[1];
  const float* ln1b = (const float*)d_in[2];
  const float* ln2g = (const float*)d_in[3];
  const float* ln2b = (const float*)d_in[4];
  const float* tmk  = (const float*)d_in[5];
  const float* tmv  = (const float*)d_in[6];
  const float* tmr  = (const float*)d_in[7];
  const float* td   = (const float*)d_in[8];
  const float* tf   = (const float*)d_in[9];
  const float* Wk   = (const float*)d_in[10];
  const float* Wv   = (const float*)d_in[11];
  const float* Wr   = (const float*)d_in[12];
  const float* Wo   = (const float*)d_in[13];
  const float* fmk  = (const float*)d_in[14];
  const float* fmr  = (const float*)d_in[15];
  const float* Fk   = (const float*)d_in[16];
  const float* Fr   = (const float*)d_in[17];
  const float* Fv   = (const float*)d_in[18];

  const int B = 8, T = 2048, C = 1024, DA = 1024, DF = 4096;
  const int M = B * T;       // 16384
  const int MQ = M / 4;      // 4096 rows per FFN quarter

  // ---- workspace layout (peak 189 MiB) ----
  char* ws = (char*)d_ws;
  const size_t MiB = 1ull << 20;
  ushort* wkb = (ushort*)(ws + 0 * MiB);
  ushort* wvb = (ushort*)(ws + 2 * MiB);
  ushort* wrb = (ushort*)(ws + 4 * MiB);
  ushort* wob = (ushort*)(ws + 6 * MiB);
  ushort* fkb = (ushort*)(ws + 8 * MiB);   // 8 MiB
  ushort* frb = (ushort*)(ws + 16 * MiB);  // 2 MiB
  ushort* fvb = (ushort*)(ws + 18 * MiB);  // 8 MiB
  ushort* bufA = (ushort*)(ws + 26 * MiB);   // xk -> v    -> xmid(lo)
  ushort* bufB = (ushort*)(ws + 58 * MiB);   // xv -> sr   -> xmid(hi)
  ushort* bufC = (ushort*)(ws + 90 * MiB);   // xr -> rwkv -> gk
  ushort* bufD = (ushort*)(ws + 122 * MiB);  // k  -> gr   -> kf(quarter)
  ushort* bufE = (ushort*)(ws + 154 * MiB);  // sig
  float*  xmid = (float*)bufA;               // 64 MiB f32 spans A+B
  float*  sAa  = (float*)(ws + 186 * MiB);
  float*  sBb  = (float*)(ws + 187 * MiB);
  float*  sPp  = (float*)(ws + 188 * MiB);

  // ---- weight converts ----
  cvt_bf16<<<(DA * C / 4 + 255) / 256, 256, 0, stream>>>(Wk, wkb, DA * C / 4);
  cvt_bf16<<<(DA * C / 4 + 255) / 256, 256, 0, stream>>>(Wv, wvb, DA * C / 4);
  cvt_bf16<<<(DA * C / 4 + 255) / 256, 256, 0, stream>>>(Wr, wrb, DA * C / 4);
  cvt_bf16<<<(C * DA / 4 + 255) / 256, 256, 0, stream>>>(Wo, wob, C * DA / 4);
  cvt_bf16<<<(DF * C / 4 + 255) / 256, 256, 0, stream>>>(Fk, fkb, DF * C / 4);
  cvt_bf16<<<(C * C / 4 + 255) / 256, 256, 0, stream>>>(Fr, frb, C * C / 4);
  cvt_bf16<<<(C * DF / 4 + 255) / 256, 256, 0, stream>>>(Fv, fvb, C * DF / 4);

  // ---- TimeMix ----
  ushort* xk = bufA; ushort* xv = bufB; ushort* xr = bufC;
  ln_mix<3><<<M, 256, 0, stream>>>(x, ln1g, ln1b, tmk, tmv, tmr, xk, xv, xr, T, C);

  ushort* kb = bufD; ushort* vb = bufA; ushort* srb = bufB; ushort* rwkv = bufC;
  dim3 gA(DA / 128, M / 128);
  gemm_bt<0><<<gA, 256, 0, stream>>>(xk, wkb, kb, nullptr, nullptr, DA, C);   // k (A dead after)
  gemm_bt<0><<<gA, 256, 0, stream>>>(xv, wvb, vb, nullptr, nullptr, DA, C);   // v -> A
  gemm_bt<1><<<gA, 256, 0, stream>>>(xr, wrb, srb, nullptr, nullptr, DA, C);  // sr -> B

  // chunk-parallel WKV
  wkv_phase1<<<(B * WKV_NCH * DA) / 256, 256, 0, stream>>>(kb, vb, td, sAa, sBb, sPp, T, DA);
  wkv_combine<<<(B * DA) / 256, 256, 0, stream>>>(td, sAa, sBb, sPp, DA);
  wkv_phase3<<<(B * WKV_NCH * DA) / 256, 256, 0, stream>>>(kb, vb, srb, td, tf, sAa, sBb, sPp, rwkv, T, DA);

  // xmid = x + rwkv @ Wo^T   (f32, spans A+B; v/sr dead)
  gemm_bt<3><<<dim3(C / 128, M / 128), 256, 0, stream>>>(rwkv, wob, xmid, x, nullptr, C, DA);

  // ---- ChannelMix ----
  ushort* gk = bufC; ushort* gr = bufD; ushort* sig = bufE;
  ln_mix<2><<<M, 256, 0, stream>>>(xmid, ln2g, ln2b, fmk, nullptr, fmr, gk, nullptr, gr, T, C);

  // sig = sigmoid(gr @ Fr^T)  -> E  (then gr dead)
  gemm_bt<1><<<dim3(C / 128, M / 128), 256, 0, stream>>>(gr, frb, sig, nullptr, nullptr, C, C);

  // FFN in 4 row-quarters to keep kf at 32 MiB (bufD, gr dead)
  ushort* kf = bufD;
  for (int q = 0; q < 4; q++) {
    const ushort* gkq = gk + (size_t)q * MQ * C;
    gemm_bt<2><<<dim3(DF / 128, MQ / 128), 256, 0, stream>>>(gkq, fkb, kf, nullptr, nullptr, DF, C);
    gemm_bt<4><<<dim3(C / 128, MQ / 128), 256, 0, stream>>>(
        kf, fvb, (float*)d_out + (size_t)q * MQ * C,
        xmid + (size_t)q * MQ * C, sig + (size_t)q * MQ * C, C, DF);
  }
}

// Round 5
// 877.971 us; speedup vs baseline: 1.6400x; 1.1485x over previous
//
#include <hip/hip_runtime.h>
#include <stdint.h>

typedef __attribute__((ext_vector_type(4))) float f32x4;
typedef __attribute__((ext_vector_type(8))) __bf16 bfv8;

__device__ __forceinline__ ushort f2bf(float f) {
  union { float f; uint32_t u; } c; c.f = f;
  uint32_t u = c.u;
  uint32_t r = (u + 0x7fffu + ((u >> 16) & 1u)) >> 16;
  return (ushort)r;
}
__device__ __forceinline__ float bf2f(ushort h) {
  union { uint32_t u; float f; } c;
  c.u = ((uint32_t)h) << 16;
  return c.f;
}

// ---------------------------------------------------------------------------
// f32 -> bf16 elementwise convert (weights)
// ---------------------------------------------------------------------------
__global__ void cvt_bf16(const float* __restrict__ src, ushort* __restrict__ dst, int n4) {
  int i = blockIdx.x * blockDim.x + threadIdx.x;
  if (i < n4) {
    float4 f = ((const float4*)src)[i];
    ushort4 o;
    o.x = f2bf(f.x); o.y = f2bf(f.y); o.z = f2bf(f.z); o.w = f2bf(f.w);
    ((ushort4*)dst)[i] = o;
  }
}

// ---------------------------------------------------------------------------
// LayerNorm + time-shift + token-mix, emitting bf16 GEMM operands.
// BI: input is bf16 (ushort) instead of f32.
// ---------------------------------------------------------------------------
template <int NOUT, bool BI>
__global__ __launch_bounds__(256)
void ln_mix(const void* __restrict__ xin, const float* __restrict__ gam,
            const float* __restrict__ bet, const float* __restrict__ mk,
            const float* __restrict__ mv, const float* __restrict__ mr,
            ushort* __restrict__ ok, ushort* __restrict__ ov,
            ushort* __restrict__ orr, int T, int C) {
  const int row = blockIdx.x;
  const int t = row % T;
  const int tid = threadIdx.x;
  float4 c4, p4 = make_float4(0.f, 0.f, 0.f, 0.f);
  if constexpr (BI) {
    const ushort4* xc = (const ushort4*)((const ushort*)xin + (size_t)row * C);
    ushort4 u = xc[tid];
    c4 = make_float4(bf2f(u.x), bf2f(u.y), bf2f(u.z), bf2f(u.w));
    if (t > 0) {
      ushort4 up = xc[tid - (C >> 2)];
      p4 = make_float4(bf2f(up.x), bf2f(up.y), bf2f(up.z), bf2f(up.w));
    }
  } else {
    const float4* xc = (const float4*)((const float*)xin + (size_t)row * C);
    c4 = xc[tid];
    if (t > 0) p4 = xc[tid - (C >> 2)];
  }

  float s = c4.x + c4.y + c4.z + c4.w;
  float ss = c4.x * c4.x + c4.y * c4.y + c4.z * c4.z + c4.w * c4.w;
  float s2 = p4.x + p4.y + p4.z + p4.w;
  float ss2 = p4.x * p4.x + p4.y * p4.y + p4.z * p4.z + p4.w * p4.w;
#pragma unroll
  for (int off = 32; off > 0; off >>= 1) {
    s += __shfl_down(s, off);
    ss += __shfl_down(ss, off);
    s2 += __shfl_down(s2, off);
    ss2 += __shfl_down(ss2, off);
  }
  __shared__ float red[4][4];
  const int wid = tid >> 6, lane = tid & 63;
  if (lane == 0) { red[wid][0] = s; red[wid][1] = ss; red[wid][2] = s2; red[wid][3] = ss2; }
  __syncthreads();
  s = red[0][0] + red[1][0] + red[2][0] + red[3][0];
  ss = red[0][1] + red[1][1] + red[2][1] + red[3][1];
  s2 = red[0][2] + red[1][2] + red[2][2] + red[3][2];
  ss2 = red[0][3] + red[1][3] + red[2][3] + red[3][3];

  const float invC = 1.0f / (float)C;
  float m1 = s * invC, v1 = ss * invC - m1 * m1;
  float rs1 = rsqrtf(v1 + 1e-5f);
  float m2 = s2 * invC, v2 = ss2 * invC - m2 * m2;
  float rs2 = rsqrtf(v2 + 1e-5f);

  const float* c4p = (const float*)&c4;
  const float* p4p = (const float*)&p4;
  ushort4 vk, vv, vr;
#pragma unroll
  for (int j = 0; j < 4; j++) {
    int col = tid * 4 + j;
    float gg = gam[col], be = bet[col];
    float hc = (c4p[j] - m1) * rs1 * gg + be;
    float hp = (t > 0) ? ((p4p[j] - m2) * rs2 * gg + be) : 0.0f;
    float fk = mk[col];
    ((ushort*)&vk)[j] = f2bf(hc * fk + hp * (1.0f - fk));
    if constexpr (NOUT == 3) {
      float fv = mv[col];
      ((ushort*)&vv)[j] = f2bf(hc * fv + hp * (1.0f - fv));
    }
    float fr = mr[col];
    ((ushort*)&vr)[j] = f2bf(hc * fr + hp * (1.0f - fr));
  }
  size_t o = (size_t)row * (C >> 2) + tid;
  ((ushort4*)ok)[o] = vk;
  if constexpr (NOUT == 3) ((ushort4*)ov)[o] = vv;
  ((ushort4*)orr)[o] = vr;
}

// ---------------------------------------------------------------------------
// bf16 MFMA GEMM: C[M,N] = A[M,K] * W[N,K]^T  (both row-major bf16)
// 128x128 tile, BK=32, 4 waves (2x2), double-buffered LDS, 2-phase pipeline,
// XCD-aware bijective block swizzle (nwg % 8 == 0 required).
// MODE 0: out bf16 = acc
// MODE 1: out bf16 = sigmoid(acc)
// MODE 2: out bf16 = relu(acc)^2
// MODE 4: out f32  = res_bf16 + mul_bf16 * acc
// MODE 5: out bf16 = res_f32 + acc
// ---------------------------------------------------------------------------
template <int MODE>
__global__ __launch_bounds__(256, 2)
void gemm_bt(const ushort* __restrict__ A, const ushort* __restrict__ W,
             void* __restrict__ outp, const void* __restrict__ res,
             const ushort* __restrict__ mul, int N, int K) {
  __shared__ ushort lA[2][4096];
  __shared__ ushort lB[2][4096];
  const int tid = threadIdx.x;
  const int wave = tid >> 6, lane = tid & 63;

  // XCD-aware swizzle: consecutive logical tiles -> same XCD (L2 reuse of A)
  const int nwg = gridDim.x * gridDim.y;
  const int bid = blockIdx.y * gridDim.x + blockIdx.x;
  const int swz = (bid & 7) * (nwg >> 3) + (bid >> 3);
  const int rowBase = (swz / gridDim.x) * 128;
  const int colBase = (swz % gridDim.x) * 128;

  const int wr = wave >> 1, wc = wave & 1;
  const int lr = lane & 15, lk = lane >> 4;

  f32x4 acc[4][4];
#pragma unroll
  for (int m = 0; m < 4; m++)
#pragma unroll
    for (int n = 0; n < 4; n++) acc[m][n] = (f32x4){0.f, 0.f, 0.f, 0.f};

  const int c0 = wave * 128 + lane;
  const int r0 = c0 >> 2, q0 = (c0 & 3) * 8;
  const int c1 = c0 + 64;
  const int r1 = c1 >> 2, q1 = (c1 & 3) * 8;

  auto stage = [&](int buf, int kt) {
    const ushort* gA0 = A + (size_t)(rowBase + r0) * K + kt + q0;
    const ushort* gA1 = A + (size_t)(rowBase + r1) * K + kt + q1;
    const ushort* gB0 = W + (size_t)(colBase + r0) * K + kt + q0;
    const ushort* gB1 = W + (size_t)(colBase + r1) * K + kt + q1;
    ushort* dA = &lA[buf][wave * 1024];
    ushort* dB = &lB[buf][wave * 1024];
    __builtin_amdgcn_global_load_lds(
        (const __attribute__((address_space(1))) void*)gA0,
        (__attribute__((address_space(3))) void*)dA, 16, 0, 0);
    __builtin_amdgcn_global_load_lds(
        (const __attribute__((address_space(1))) void*)gA1,
        (__attribute__((address_space(3))) void*)(dA + 512), 16, 0, 0);
    __builtin_amdgcn_global_load_lds(
        (const __attribute__((address_space(1))) void*)gB0,
        (__attribute__((address_space(3))) void*)dB, 16, 0, 0);
    __builtin_amdgcn_global_load_lds(
        (const __attribute__((address_space(1))) void*)gB1,
        (__attribute__((address_space(3))) void*)(dB + 512), 16, 0, 0);
  };

  auto compute = [&](int buf) {
    bfv8 af[4], bfr[4];
#pragma unroll
    for (int m = 0; m < 4; m++)
      af[m] = *(const bfv8*)(&lA[buf][(wr * 64 + m * 16 + lr) * 32 + lk * 8]);
#pragma unroll
    for (int n = 0; n < 4; n++)
      bfr[n] = *(const bfv8*)(&lB[buf][(wc * 64 + n * 16 + lr) * 32 + lk * 8]);
#pragma unroll
    for (int m = 0; m < 4; m++)
#pragma unroll
      for (int n = 0; n < 4; n++)
        acc[m][n] = __builtin_amdgcn_mfma_f32_16x16x32_bf16(af[m], bfr[n], acc[m][n], 0, 0, 0);
  };

  stage(0, 0);
  __syncthreads();
  int cur = 0;
  for (int kt = 0; kt + 32 < K; kt += 32) {
    stage(cur ^ 1, kt + 32);
    compute(cur);
    __syncthreads();
    cur ^= 1;
  }
  compute(cur);

#pragma unroll
  for (int m = 0; m < 4; m++) {
#pragma unroll
    for (int j = 0; j < 4; j++) {
      int row = rowBase + wr * 64 + m * 16 + lk * 4 + j;
#pragma unroll
      for (int n = 0; n < 4; n++) {
        int col = colBase + wc * 64 + n * 16 + lr;
        float v = acc[m][n][j];
        size_t idx = (size_t)row * N + col;
        if constexpr (MODE == 0) {
          ((ushort*)outp)[idx] = f2bf(v);
        } else if constexpr (MODE == 1) {
          ((ushort*)outp)[idx] = f2bf(1.0f / (1.0f + __expf(-v)));
        } else if constexpr (MODE == 2) {
          float r = fmaxf(v, 0.0f);
          ((ushort*)outp)[idx] = f2bf(r * r);
        } else if constexpr (MODE == 4) {
          ((float*)outp)[idx] = bf2f(((const ushort*)res)[idx]) + bf2f(mul[idx]) * v;
        } else {  // MODE 5
          ((ushort*)outp)[idx] = f2bf(((const float*)res)[idx] + v);
        }
      }
    }
  }
}

// ---------------------------------------------------------------------------
// WKV chunk-parallel scan. T split into NCH chunks of L.
// ---------------------------------------------------------------------------
#define WKV_NCH 32
#define WKV_L 64

__global__ __launch_bounds__(256)
void wkv_phase1(const ushort* __restrict__ k, const ushort* __restrict__ v,
                const float* __restrict__ td,
                float* __restrict__ sA, float* __restrict__ sB, float* __restrict__ sP,
                int T, int D) {
  int id = blockIdx.x * 256 + threadIdx.x;  // ((b*NCH + c)*D + d)
  int d = id % D;
  int bc = id / D;
  int c = bc % WKV_NCH;
  int b = bc / WKV_NCH;
  float w = -__expf(td[d]);
  float a = 0.f, bb = 0.f, p = -1e30f;
  const size_t base = (size_t)b * T * D + (size_t)c * WKV_L * D + d;
#pragma unroll 4
  for (int t = 0; t < WKV_L; t++) {
    size_t idx = base + (size_t)t * D;
    float kt = bf2f(k[idx]), vt = bf2f(v[idx]);
    float ww2 = p + w;
    float q2 = fmaxf(ww2, kt);
    float e1b = __expf(ww2 - q2), e2b = __expf(kt - q2);
    a = e1b * a + e2b * vt;
    bb = e1b * bb + e2b;
    p = q2;
  }
  sA[id] = a; sB[id] = bb; sP[id] = p;
}

__global__ __launch_bounds__(256)
void wkv_combine(const float* __restrict__ td,
                 float* __restrict__ sA, float* __restrict__ sB, float* __restrict__ sP,
                 int D) {
  int id = blockIdx.x * 256 + threadIdx.x;  // b*D + d
  int d = id % D;
  int b = id / D;
  float w = -__expf(td[d]);
  float Lw = (float)WKV_L * w;
  float a = 0.f, bb = 0.f, p = -1e30f;
  for (int c = 0; c < WKV_NCH; c++) {
    size_t idx = ((size_t)b * WKV_NCH + c) * D + d;
    float la = sA[idx], lb = sB[idx], lp = sP[idx];
    sA[idx] = a; sB[idx] = bb; sP[idx] = p;
    float pd = p + Lw;
    float q = fmaxf(pd, lp);
    float e1 = __expf(pd - q), e2 = __expf(lp - q);
    a = e1 * a + e2 * la;
    bb = e1 * bb + e2 * lb;
    p = q;
  }
}

__global__ __launch_bounds__(256)
void wkv_phase3(const ushort* __restrict__ k, const ushort* __restrict__ v,
                const ushort* __restrict__ sr, const float* __restrict__ td,
                const float* __restrict__ tf,
                const float* __restrict__ sA, const float* __restrict__ sB,
                const float* __restrict__ sP, ushort* __restrict__ out,
                int T, int D) {
  int id = blockIdx.x * 256 + threadIdx.x;  // ((b*NCH + c)*D + d)
  int d = id % D;
  int bc = id / D;
  int c = bc % WKV_NCH;
  int b = bc / WKV_NCH;
  float w = -__expf(td[d]);
  float u = tf[d];
  float a = sA[id], bb = sB[id], p = sP[id];
  const size_t base = (size_t)b * T * D + (size_t)c * WKV_L * D + d;
#pragma unroll 2
  for (int t = 0; t < WKV_L; t++) {
    size_t idx = base + (size_t)t * D;
    float kt = bf2f(k[idx]), vt = bf2f(v[idx]);
    float ww = u + kt;
    float q = fmaxf(p, ww);
    float e1 = __expf(p - q), e2 = __expf(ww - q);
    float y = (e1 * a + e2 * vt) / (e1 * bb + e2);
    out[idx] = f2bf(bf2f(sr[idx]) * y);
    float ww2 = p + w;
    float q2 = fmaxf(ww2, kt);
    float e1b = __expf(ww2 - q2), e2b = __expf(kt - q2);
    a = e1b * a + e2b * vt;
    bb = e1b * bb + e2b;
    p = q2;
  }
}

// ---------------------------------------------------------------------------
extern "C" void kernel_launch(void* const* d_in, const int* in_sizes, int n_in,
                              void* d_out, int out_size, void* d_ws, size_t ws_size,
                              hipStream_t stream) {
  (void)in_sizes; (void)n_in; (void)out_size; (void)ws_size;
  const float* x    = (const float*)d_in[0];
  const float* ln1g = (const float*)d_in[1];
  const float* ln1b = (const float*)d_in[2];
  const float* ln2g = (const float*)d_in[3];
  const float* ln2b = (const float*)d_in[4];
  const float* tmk  = (const float*)d_in[5];
  const float* tmv  = (const float*)d_in[6];
  const float* tmr  = (const float*)d_in[7];
  const float* td   = (const float*)d_in[8];
  const float* tf   = (const float*)d_in[9];
  const float* Wk   = (const float*)d_in[10];
  const float* Wv   = (const float*)d_in[11];
  const float* Wr   = (const float*)d_in[12];
  const float* Wo   = (const float*)d_in[13];
  const float* fmk  = (const float*)d_in[14];
  const float* fmr  = (const float*)d_in[15];
  const float* Fk   = (const float*)d_in[16];
  const float* Fr   = (const float*)d_in[17];
  const float* Fv   = (const float*)d_in[18];

  const int B = 8, T = 2048, C = 1024, DA = 1024, DF = 4096;
  const int M = B * T;       // 16384
  const int MH = M / 2;      // 8192 rows per FFN half

  // ---- workspace layout (peak 189 MiB) ----
  char* ws = (char*)d_ws;
  const size_t MiB = 1ull << 20;
  ushort* wkb = (ushort*)(ws + 0 * MiB);
  ushort* wvb = (ushort*)(ws + 2 * MiB);
  ushort* wrb = (ushort*)(ws + 4 * MiB);
  ushort* wob = (ushort*)(ws + 6 * MiB);
  ushort* fkb = (ushort*)(ws + 8 * MiB);   // 8 MiB
  ushort* frb = (ushort*)(ws + 16 * MiB);  // 2 MiB
  ushort* fvb = (ushort*)(ws + 18 * MiB);  // 8 MiB
  ushort* bufA = (ushort*)(ws + 26 * MiB);   // xk -> v    -> xmid(bf16)
  ushort* bufB = (ushort*)(ws + 58 * MiB);   // xv -> sr   -> gk
  ushort* bufC = (ushort*)(ws + 90 * MiB);   // xr -> rwkv -> kf(lo)
  ushort* bufD = (ushort*)(ws + 122 * MiB);  // k  -> gr   -> kf(hi)
  ushort* bufE = (ushort*)(ws + 154 * MiB);  // sig
  float*  sAa  = (float*)(ws + 186 * MiB);
  float*  sBb  = (float*)(ws + 187 * MiB);
  float*  sPp  = (float*)(ws + 188 * MiB);

  // ---- weight converts ----
  cvt_bf16<<<(DA * C / 4 + 255) / 256, 256, 0, stream>>>(Wk, wkb, DA * C / 4);
  cvt_bf16<<<(DA * C / 4 + 255) / 256, 256, 0, stream>>>(Wv, wvb, DA * C / 4);
  cvt_bf16<<<(DA * C / 4 + 255) / 256, 256, 0, stream>>>(Wr, wrb, DA * C / 4);
  cvt_bf16<<<(C * DA / 4 + 255) / 256, 256, 0, stream>>>(Wo, wob, C * DA / 4);
  cvt_bf16<<<(DF * C / 4 + 255) / 256, 256, 0, stream>>>(Fk, fkb, DF * C / 4);
  cvt_bf16<<<(C * C / 4 + 255) / 256, 256, 0, stream>>>(Fr, frb, C * C / 4);
  cvt_bf16<<<(C * DF / 4 + 255) / 256, 256, 0, stream>>>(Fv, fvb, C * DF / 4);

  // ---- TimeMix ----
  ushort* xk = bufA; ushort* xv = bufB; ushort* xr = bufC;
  ln_mix<3, false><<<M, 256, 0, stream>>>(x, ln1g, ln1b, tmk, tmv, tmr, xk, xv, xr, T, C);

  ushort* kb = bufD; ushort* vb = bufA; ushort* srb = bufB; ushort* rwkv = bufC;
  dim3 gA(DA / 128, M / 128);
  gemm_bt<0><<<gA, 256, 0, stream>>>(xk, wkb, kb, nullptr, nullptr, DA, C);   // k -> D
  gemm_bt<0><<<gA, 256, 0, stream>>>(xv, wvb, vb, nullptr, nullptr, DA, C);   // v -> A
  gemm_bt<1><<<gA, 256, 0, stream>>>(xr, wrb, srb, nullptr, nullptr, DA, C);  // sr -> B

  wkv_phase1<<<(B * WKV_NCH * DA) / 256, 256, 0, stream>>>(kb, vb, td, sAa, sBb, sPp, T, DA);
  wkv_combine<<<(B * DA) / 256, 256, 0, stream>>>(td, sAa, sBb, sPp, DA);
  wkv_phase3<<<(B * WKV_NCH * DA) / 256, 256, 0, stream>>>(kb, vb, srb, td, tf, sAa, sBb, sPp, rwkv, T, DA);

  // xmid(bf16) = x + rwkv @ Wo^T  -> bufA (v dead)
  ushort* xmidb = bufA;
  gemm_bt<5><<<dim3(C / 128, M / 128), 256, 0, stream>>>(rwkv, wob, xmidb, x, nullptr, C, DA);

  // ---- ChannelMix ----
  ushort* gk = bufB; ushort* gr = bufD; ushort* sig = bufE;
  ln_mix<2, true><<<M, 256, 0, stream>>>(xmidb, ln2g, ln2b, fmk, nullptr, fmr, gk, nullptr, gr, T, C);

  // sig = sigmoid(gr @ Fr^T) -> E  (gr dead after)
  gemm_bt<1><<<dim3(C / 128, M / 128), 256, 0, stream>>>(gr, frb, sig, nullptr, nullptr, C, C);

  // FFN in 2 row-halves; kf half = 64 MiB spanning bufC+bufD (rwkv, gr dead)
  ushort* kf = bufC;
  for (int h = 0; h < 2; h++) {
    const ushort* gkh = gk + (size_t)h * MH * C;
    gemm_bt<2><<<dim3(DF / 128, MH / 128), 256, 0, stream>>>(gkh, fkb, kf, nullptr, nullptr, DF, C);
    gemm_bt<4><<<dim3(C / 128, MH / 128), 256, 0, stream>>>(
        kf, fvb, (float*)d_out + (size_t)h * MH * C,
        xmidb + (size_t)h * MH * C, sig + (size_t)h * MH * C, C, DF);
  }
}

// Round 6
// 773.519 us; speedup vs baseline: 1.8615x; 1.1350x over previous
//
#include <hip/hip_runtime.h>
#include <stdint.h>

typedef __attribute__((ext_vector_type(4))) float f32x4;
typedef __attribute__((ext_vector_type(8))) __bf16 bfv8;

__device__ __forceinline__ ushort f2bf(float f) {
  union { float f; uint32_t u; } c; c.f = f;
  uint32_t u = c.u;
  uint32_t r = (u + 0x7fffu + ((u >> 16) & 1u)) >> 16;
  return (ushort)r;
}
__device__ __forceinline__ float bf2f(ushort h) {
  union { uint32_t u; float f; } c;
  c.u = ((uint32_t)h) << 16;
  return c.f;
}

// ---------------------------------------------------------------------------
// f32 -> bf16 elementwise convert (weights)
// ---------------------------------------------------------------------------
__global__ void cvt_bf16(const float* __restrict__ src, ushort* __restrict__ dst, int n4) {
  int i = blockIdx.x * blockDim.x + threadIdx.x;
  if (i < n4) {
    float4 f = ((const float4*)src)[i];
    ushort4 o;
    o.x = f2bf(f.x); o.y = f2bf(f.y); o.z = f2bf(f.z); o.w = f2bf(f.w);
    ((ushort4*)dst)[i] = o;
  }
}

// ---------------------------------------------------------------------------
// LayerNorm + time-shift + token-mix, emitting bf16 GEMM operands.
// ---------------------------------------------------------------------------
template <int NOUT, bool BI>
__global__ __launch_bounds__(256)
void ln_mix(const void* __restrict__ xin, const float* __restrict__ gam,
            const float* __restrict__ bet, const float* __restrict__ mk,
            const float* __restrict__ mv, const float* __restrict__ mr,
            ushort* __restrict__ ok, ushort* __restrict__ ov,
            ushort* __restrict__ orr, int T, int C) {
  const int row = blockIdx.x;
  const int t = row % T;
  const int tid = threadIdx.x;
  float4 c4, p4 = make_float4(0.f, 0.f, 0.f, 0.f);
  if constexpr (BI) {
    const ushort4* xc = (const ushort4*)((const ushort*)xin + (size_t)row * C);
    ushort4 u = xc[tid];
    c4 = make_float4(bf2f(u.x), bf2f(u.y), bf2f(u.z), bf2f(u.w));
    if (t > 0) {
      ushort4 up = xc[tid - (C >> 2)];
      p4 = make_float4(bf2f(up.x), bf2f(up.y), bf2f(up.z), bf2f(up.w));
    }
  } else {
    const float4* xc = (const float4*)((const float*)xin + (size_t)row * C);
    c4 = xc[tid];
    if (t > 0) p4 = xc[tid - (C >> 2)];
  }

  float s = c4.x + c4.y + c4.z + c4.w;
  float ss = c4.x * c4.x + c4.y * c4.y + c4.z * c4.z + c4.w * c4.w;
  float s2 = p4.x + p4.y + p4.z + p4.w;
  float ss2 = p4.x * p4.x + p4.y * p4.y + p4.z * p4.z + p4.w * p4.w;
#pragma unroll
  for (int off = 32; off > 0; off >>= 1) {
    s += __shfl_down(s, off);
    ss += __shfl_down(ss, off);
    s2 += __shfl_down(s2, off);
    ss2 += __shfl_down(ss2, off);
  }
  __shared__ float red[4][4];
  const int wid = tid >> 6, lane = tid & 63;
  if (lane == 0) { red[wid][0] = s; red[wid][1] = ss; red[wid][2] = s2; red[wid][3] = ss2; }
  __syncthreads();
  s = red[0][0] + red[1][0] + red[2][0] + red[3][0];
  ss = red[0][1] + red[1][1] + red[2][1] + red[3][1];
  s2 = red[0][2] + red[1][2] + red[2][2] + red[3][2];
  ss2 = red[0][3] + red[1][3] + red[2][3] + red[3][3];

  const float invC = 1.0f / (float)C;
  float m1 = s * invC, v1 = ss * invC - m1 * m1;
  float rs1 = rsqrtf(v1 + 1e-5f);
  float m2 = s2 * invC, v2 = ss2 * invC - m2 * m2;
  float rs2 = rsqrtf(v2 + 1e-5f);

  const float* c4p = (const float*)&c4;
  const float* p4p = (const float*)&p4;
  ushort4 vk, vv, vr;
#pragma unroll
  for (int j = 0; j < 4; j++) {
    int col = tid * 4 + j;
    float gg = gam[col], be = bet[col];
    float hc = (c4p[j] - m1) * rs1 * gg + be;
    float hp = (t > 0) ? ((p4p[j] - m2) * rs2 * gg + be) : 0.0f;
    float fk = mk[col];
    ((ushort*)&vk)[j] = f2bf(hc * fk + hp * (1.0f - fk));
    if constexpr (NOUT == 3) {
      float fv = mv[col];
      ((ushort*)&vv)[j] = f2bf(hc * fv + hp * (1.0f - fv));
    }
    float fr = mr[col];
    ((ushort*)&vr)[j] = f2bf(hc * fr + hp * (1.0f - fr));
  }
  size_t o = (size_t)row * (C >> 2) + tid;
  ((ushort4*)ok)[o] = vk;
  if constexpr (NOUT == 3) ((ushort4*)ov)[o] = vv;
  ((ushort4*)orr)[o] = vr;
}

// ---------------------------------------------------------------------------
// 256x256 bf16 MFMA GEMM, counted-vmcnt phase schedule.
// C[M,N] = A[M,K] * W[N,K]^T (row-major bf16). 512 threads = 8 waves (2Mx4N),
// per-wave 128x64 output (8x4 16x16x32 frags). BK=32, 3-slot LDS ring
// (96 KiB), 2-K-tile lookahead: iteration-end s_waitcnt vmcnt(4) keeps the
// next-next tile's loads in flight (never drains to 0 mid-loop).
// LDS XOR-swizzle byte^=((row>>1)&3)<<4 applied on BOTH sides: inverse-
// swizzled global source (global_load_lds writes linearly) + swizzled ds_read.
// Raw s_barrier pins phases; s_setprio(1) wraps each MFMA cluster.
// MODE 0: out bf16 = acc ; 1: bf16 sigmoid(acc) ; 2: bf16 relu(acc)^2 ;
// MODE 4: out f32 = res_bf16 + mul_bf16*acc ; 5: out bf16 = res_f32 + acc
// ---------------------------------------------------------------------------
template <int MODE>
__global__ __launch_bounds__(512, 2)
void gemm256(const ushort* __restrict__ A, const ushort* __restrict__ W,
             void* __restrict__ outp, const void* __restrict__ res,
             const ushort* __restrict__ mul, int N, int K) {
  __shared__ ushort lds[3 * 16384];  // slot = A[256x32] (8192) + B[256x32] (8192)
  const int tid = threadIdx.x;
  const int wave = tid >> 6, lane = tid & 63;
  const int nwg = gridDim.x * gridDim.y;
  const int bid = blockIdx.y * gridDim.x + blockIdx.x;
  const int swzb = (bid & 7) * (nwg >> 3) + (bid >> 3);
  const int rowBase = (swzb / gridDim.x) * 256;
  const int colBase = (swzb % gridDim.x) * 256;
  const int wr = wave >> 2, wc = wave & 3;
  const int lr = lane & 15, lk = lane >> 4;

  f32x4 acc[8][4];
#pragma unroll
  for (int m = 0; m < 8; m++)
#pragma unroll
    for (int n = 0; n < 4; n++) acc[m][n] = (f32x4){0.f, 0.f, 0.f, 0.f};

  const int NT = K >> 5;

  // stage one 16B chunk pair (A+B) for K-tile at column kt into slot s.
  // chunk c = (wave*2+j)*64 + lane; logical row r=c>>2, col-slot q=c&3.
  // LDS dest is linear (base + lane*16); source col is inverse-swizzled.
  auto stage = [&](int s, int kt, int j) {
    int c = (wave * 2 + j) * 64 + lane;
    int r = c >> 2;
    int cb = ((c & 3) << 4) ^ (((r >> 1) & 3) << 4);  // swizzled byte-in-row
    const ushort* srcA = A + (size_t)(rowBase + r) * K + kt + (cb >> 1);
    const ushort* srcB = W + (size_t)(colBase + r) * K + kt + (cb >> 1);
    ushort* dA = &lds[s * 16384 + (wave * 2 + j) * 512];
    __builtin_amdgcn_global_load_lds(
        (const __attribute__((address_space(1))) void*)srcA,
        (__attribute__((address_space(3))) void*)dA, 16, 0, 0);
    __builtin_amdgcn_global_load_lds(
        (const __attribute__((address_space(1))) void*)srcB,
        (__attribute__((address_space(3))) void*)(dA + 8192), 16, 0, 0);
  };

  // prologue: tiles 0,1 -> slots 0,1 ; wait tile0 (4 oldest), keep tile1 flying
  stage(0, 0, 0); stage(0, 0, 1);
  stage(1, 32, 0); stage(1, 32, 1);
  asm volatile("s_waitcnt vmcnt(4)" ::: "memory");
  __builtin_amdgcn_s_barrier();

  int cs = 0;
  for (int t = 0; t < NT; ++t) {
    const int ns = (cs + 2 >= 3) ? cs - 1 : cs + 2;  // (cs+2)%3
    const ushort* As = &lds[cs * 16384];
    const ushort* Bs = As + 8192;
    const bool doStage = (t + 2) < NT;
    const int kt2 = (t + 2) << 5;

    bfv8 af[4], bfr[4];
    // ---- phase 0: stage j0 of tile t+2 ; frags m0-3 + all B ; 16 MFMA ----
    if (doStage) stage(ns, kt2, 0);
#pragma unroll
    for (int m = 0; m < 4; m++) {
      int row = wr * 128 + m * 16 + lr;
      af[m] = *(const bfv8*)(As + row * 32 + ((lk * 8) ^ (((row >> 1) & 3) << 3)));
    }
#pragma unroll
    for (int n = 0; n < 4; n++) {
      int row = wc * 64 + n * 16 + lr;
      bfr[n] = *(const bfv8*)(Bs + row * 32 + ((lk * 8) ^ (((row >> 1) & 3) << 3)));
    }
    __builtin_amdgcn_s_barrier();
    __builtin_amdgcn_s_setprio(1);
#pragma unroll
    for (int m = 0; m < 4; m++)
#pragma unroll
      for (int n = 0; n < 4; n++)
        acc[m][n] = __builtin_amdgcn_mfma_f32_16x16x32_bf16(af[m], bfr[n], acc[m][n], 0, 0, 0);
    __builtin_amdgcn_s_setprio(0);
    __builtin_amdgcn_s_barrier();

    // ---- phase 1: stage j1 ; frags m4-7 (reuse B) ; 16 MFMA ----
    if (doStage) stage(ns, kt2, 1);
#pragma unroll
    for (int m = 0; m < 4; m++) {
      int row = wr * 128 + (m + 4) * 16 + lr;
      af[m] = *(const bfv8*)(As + row * 32 + ((lk * 8) ^ (((row >> 1) & 3) << 3)));
    }
    __builtin_amdgcn_s_barrier();
    __builtin_amdgcn_s_setprio(1);
#pragma unroll
    for (int m = 0; m < 4; m++)
#pragma unroll
      for (int n = 0; n < 4; n++)
        acc[m + 4][n] = __builtin_amdgcn_mfma_f32_16x16x32_bf16(af[m], bfr[n], acc[m + 4][n], 0, 0, 0);
    __builtin_amdgcn_s_setprio(0);
    // iteration end: previous tile's 4 loads must have landed; keep the
    // newest 4 (tile t+2) in flight.
    if (doStage) { asm volatile("s_waitcnt vmcnt(4)" ::: "memory"); }
    else         { asm volatile("s_waitcnt vmcnt(0)" ::: "memory"); }
    __builtin_amdgcn_s_barrier();
    cs = (cs == 2) ? 0 : cs + 1;
  }

  // ---- epilogue ----
#pragma unroll
  for (int m = 0; m < 8; m++) {
#pragma unroll
    for (int j = 0; j < 4; j++) {
      int row = rowBase + wr * 128 + m * 16 + lk * 4 + j;
#pragma unroll
      for (int n = 0; n < 4; n++) {
        int col = colBase + wc * 64 + n * 16 + lr;
        float v = acc[m][n][j];
        size_t idx = (size_t)row * N + col;
        if constexpr (MODE == 0) {
          ((ushort*)outp)[idx] = f2bf(v);
        } else if constexpr (MODE == 1) {
          ((ushort*)outp)[idx] = f2bf(1.0f / (1.0f + __expf(-v)));
        } else if constexpr (MODE == 2) {
          float r = fmaxf(v, 0.0f);
          ((ushort*)outp)[idx] = f2bf(r * r);
        } else if constexpr (MODE == 4) {
          ((float*)outp)[idx] = bf2f(((const ushort*)res)[idx]) + bf2f(mul[idx]) * v;
        } else {  // MODE 5
          ((ushort*)outp)[idx] = f2bf(((const float*)res)[idx] + v);
        }
      }
    }
  }
}

// ---------------------------------------------------------------------------
// WKV chunk-parallel scan. T split into NCH chunks of L.
// ---------------------------------------------------------------------------
#define WKV_NCH 32
#define WKV_L 64

__global__ __launch_bounds__(256)
void wkv_phase1(const ushort* __restrict__ k, const ushort* __restrict__ v,
                const float* __restrict__ td,
                float* __restrict__ sA, float* __restrict__ sB, float* __restrict__ sP,
                int T, int D) {
  int id = blockIdx.x * 256 + threadIdx.x;  // ((b*NCH + c)*D + d)
  int d = id % D;
  int bc = id / D;
  int c = bc % WKV_NCH;
  int b = bc / WKV_NCH;
  float w = -__expf(td[d]);
  float a = 0.f, bb = 0.f, p = -1e30f;
  const size_t base = (size_t)b * T * D + (size_t)c * WKV_L * D + d;
#pragma unroll 4
  for (int t = 0; t < WKV_L; t++) {
    size_t idx = base + (size_t)t * D;
    float kt = bf2f(k[idx]), vt = bf2f(v[idx]);
    float ww2 = p + w;
    float q2 = fmaxf(ww2, kt);
    float e1b = __expf(ww2 - q2), e2b = __expf(kt - q2);
    a = e1b * a + e2b * vt;
    bb = e1b * bb + e2b;
    p = q2;
  }
  sA[id] = a; sB[id] = bb; sP[id] = p;
}

__global__ __launch_bounds__(256)
void wkv_combine(const float* __restrict__ td,
                 float* __restrict__ sA, float* __restrict__ sB, float* __restrict__ sP,
                 int D) {
  int id = blockIdx.x * 256 + threadIdx.x;  // b*D + d
  int d = id % D;
  int b = id / D;
  float w = -__expf(td[d]);
  float Lw = (float)WKV_L * w;
  float a = 0.f, bb = 0.f, p = -1e30f;
  for (int c = 0; c < WKV_NCH; c++) {
    size_t idx = ((size_t)b * WKV_NCH + c) * D + d;
    float la = sA[idx], lb = sB[idx], lp = sP[idx];
    sA[idx] = a; sB[idx] = bb; sP[idx] = p;
    float pd = p + Lw;
    float q = fmaxf(pd, lp);
    float e1 = __expf(pd - q), e2 = __expf(lp - q);
    a = e1 * a + e2 * la;
    bb = e1 * bb + e2 * lb;
    p = q;
  }
}

__global__ __launch_bounds__(256)
void wkv_phase3(const ushort* __restrict__ k, const ushort* __restrict__ v,
                const ushort* __restrict__ sr, const float* __restrict__ td,
                const float* __restrict__ tf,
                const float* __restrict__ sA, const float* __restrict__ sB,
                const float* __restrict__ sP, ushort* __restrict__ out,
                int T, int D) {
  int id = blockIdx.x * 256 + threadIdx.x;  // ((b*NCH + c)*D + d)
  int d = id % D;
  int bc = id / D;
  int c = bc % WKV_NCH;
  int b = bc / WKV_NCH;
  float w = -__expf(td[d]);
  float u = tf[d];
  float a = sA[id], bb = sB[id], p = sP[id];
  const size_t base = (size_t)b * T * D + (size_t)c * WKV_L * D + d;
#pragma unroll 2
  for (int t = 0; t < WKV_L; t++) {
    size_t idx = base + (size_t)t * D;
    float kt = bf2f(k[idx]), vt = bf2f(v[idx]);
    float ww = u + kt;
    float q = fmaxf(p, ww);
    float e1 = __expf(p - q), e2 = __expf(ww - q);
    float y = (e1 * a + e2 * vt) / (e1 * bb + e2);
    out[idx] = f2bf(bf2f(sr[idx]) * y);
    float ww2 = p + w;
    float q2 = fmaxf(ww2, kt);
    float e1b = __expf(ww2 - q2), e2b = __expf(kt - q2);
    a = e1b * a + e2b * vt;
    bb = e1b * bb + e2b;
    p = q2;
  }
}

// ---------------------------------------------------------------------------
extern "C" void kernel_launch(void* const* d_in, const int* in_sizes, int n_in,
                              void* d_out, int out_size, void* d_ws, size_t ws_size,
                              hipStream_t stream) {
  (void)in_sizes; (void)n_in; (void)out_size;
  const float* x    = (const float*)d_in[0];
  const float* ln1g = (const float*)d_in[1];
  const float* ln1b = (const float*)d_in[2];
  const float* ln2g = (const float*)d_in[3];
  const float* ln2b = (const float*)d_in[4];
  const float* tmk  = (const float*)d_in[5];
  const float* tmv  = (const float*)d_in[6];
  const float* tmr  = (const float*)d_in[7];
  const float* td   = (const float*)d_in[8];
  const float* tf   = (const float*)d_in[9];
  const float* Wk   = (const float*)d_in[10];
  const float* Wv   = (const float*)d_in[11];
  const float* Wr   = (const float*)d_in[12];
  const float* Wo   = (const float*)d_in[13];
  const float* fmk  = (const float*)d_in[14];
  const float* fmr  = (const float*)d_in[15];
  const float* Fk   = (const float*)d_in[16];
  const float* Fr   = (const float*)d_in[17];
  const float* Fv   = (const float*)d_in[18];

  const int B = 8, T = 2048, C = 1024, DA = 1024, DF = 4096;
  const int M = B * T;       // 16384
  const int MH = M / 2;      // 8192

  const bool fullffn = ws_size >= (251ull << 20);

  char* ws = (char*)d_ws;
  const size_t MiB = 1ull << 20;
  ushort* wkb = (ushort*)(ws + 0 * MiB);
  ushort* wvb = (ushort*)(ws + 2 * MiB);
  ushort* wrb = (ushort*)(ws + 4 * MiB);
  ushort* wob = (ushort*)(ws + 6 * MiB);
  ushort* fkb = (ushort*)(ws + 8 * MiB);
  ushort* frb = (ushort*)(ws + 16 * MiB);
  ushort* fvb = (ushort*)(ws + 18 * MiB);
  ushort* bufA = (ushort*)(ws + 26 * MiB);   // xk -> v    -> xmid(bf16)
  ushort* bufB = (ushort*)(ws + 58 * MiB);   // xv -> sr   -> gk
  ushort* bufC = (ushort*)(ws + 90 * MiB);   // xr -> rwkv -> kf
  ushort* bufD = (ushort*)(ws + 122 * MiB);  // k  -> gr   -> kf(cont.)
  // halves path: sig at 154, wkv states at 186
  // full path:  kf spans 90..218, sig at 218, wkv states at 154
  float* sAa; float* sBb; float* sPp; ushort* sig;
  if (fullffn) {
    sAa = (float*)(ws + 154 * MiB);
    sBb = (float*)(ws + 155 * MiB);
    sPp = (float*)(ws + 156 * MiB);
    sig = (ushort*)(ws + 218 * MiB);
  } else {
    sig = (ushort*)(ws + 154 * MiB);
    sAa = (float*)(ws + 186 * MiB);
    sBb = (float*)(ws + 187 * MiB);
    sPp = (float*)(ws + 188 * MiB);
  }

  // ---- weight converts ----
  cvt_bf16<<<(DA * C / 4 + 255) / 256, 256, 0, stream>>>(Wk, wkb, DA * C / 4);
  cvt_bf16<<<(DA * C / 4 + 255) / 256, 256, 0, stream>>>(Wv, wvb, DA * C / 4);
  cvt_bf16<<<(DA * C / 4 + 255) / 256, 256, 0, stream>>>(Wr, wrb, DA * C / 4);
  cvt_bf16<<<(C * DA / 4 + 255) / 256, 256, 0, stream>>>(Wo, wob, C * DA / 4);
  cvt_bf16<<<(DF * C / 4 + 255) / 256, 256, 0, stream>>>(Fk, fkb, DF * C / 4);
  cvt_bf16<<<(C * C / 4 + 255) / 256, 256, 0, stream>>>(Fr, frb, C * C / 4);
  cvt_bf16<<<(C * DF / 4 + 255) / 256, 256, 0, stream>>>(Fv, fvb, C * DF / 4);

  // ---- TimeMix ----
  ushort* xk = bufA; ushort* xv = bufB; ushort* xr = bufC;
  ln_mix<3, false><<<M, 256, 0, stream>>>(x, ln1g, ln1b, tmk, tmv, tmr, xk, xv, xr, T, C);

  ushort* kb = bufD; ushort* vb = bufA; ushort* srb = bufB; ushort* rwkv = bufC;
  dim3 gQ(DA / 256, M / 256);
  gemm256<0><<<gQ, 512, 0, stream>>>(xk, wkb, kb, nullptr, nullptr, DA, C);
  gemm256<0><<<gQ, 512, 0, stream>>>(xv, wvb, vb, nullptr, nullptr, DA, C);
  gemm256<1><<<gQ, 512, 0, stream>>>(xr, wrb, srb, nullptr, nullptr, DA, C);

  wkv_phase1<<<(B * WKV_NCH * DA) / 256, 256, 0, stream>>>(kb, vb, td, sAa, sBb, sPp, T, DA);
  wkv_combine<<<(B * DA) / 256, 256, 0, stream>>>(td, sAa, sBb, sPp, DA);
  wkv_phase3<<<(B * WKV_NCH * DA) / 256, 256, 0, stream>>>(kb, vb, srb, td, tf, sAa, sBb, sPp, rwkv, T, DA);

  // xmid(bf16) = x + rwkv @ Wo^T  -> bufA
  ushort* xmidb = bufA;
  gemm256<5><<<dim3(C / 256, M / 256), 512, 0, stream>>>(rwkv, wob, xmidb, x, nullptr, C, DA);

  // ---- ChannelMix ----
  ushort* gk = bufB; ushort* gr = bufD;
  ln_mix<2, true><<<M, 256, 0, stream>>>(xmidb, ln2g, ln2b, fmk, nullptr, fmr, gk, nullptr, gr, T, C);

  // sig = sigmoid(gr @ Fr^T)  (gr dead after)
  gemm256<1><<<dim3(C / 256, M / 256), 512, 0, stream>>>(gr, frb, sig, nullptr, nullptr, C, C);

  ushort* kf = bufC;  // halves: 64 MiB (bufC+bufD); full: 128 MiB (90..218)
  if (fullffn) {
    gemm256<2><<<dim3(DF / 256, M / 256), 512, 0, stream>>>(gk, fkb, kf, nullptr, nullptr, DF, C);
    gemm256<4><<<dim3(C / 256, M / 256), 512, 0, stream>>>(kf, fvb, (float*)d_out, xmidb, sig, C, DF);
  } else {
    for (int h = 0; h < 2; h++) {
      const ushort* gkh = gk + (size_t)h * MH * C;
      gemm256<2><<<dim3(DF / 256, MH / 256), 512, 0, stream>>>(gkh, fkb, kf, nullptr, nullptr, DF, C);
      gemm256<4><<<dim3(C / 256, MH / 256), 512, 0, stream>>>(
          kf, fvb, (float*)d_out + (size_t)h * MH * C,
          xmidb + (size_t)h * MH * C, sig + (size_t)h * MH * C, C, DF);
    }
  }
}